// Round 1
// baseline (460.641 us; speedup 1.0000x reference)
//
#include <hip/hip_runtime.h>
#include <hip/hip_bf16.h>
#include <cstdint>
#include <cstddef>

// ---------- types ----------
typedef __bf16 bf16x8 __attribute__((ext_vector_type(8)));
typedef float f32x4 __attribute__((ext_vector_type(4)));

__device__ __forceinline__ unsigned short f2bf(float f) {
    unsigned u = __builtin_bit_cast(unsigned, f);
    u += 0x7FFFu + ((u >> 16) & 1u);   // round-to-nearest-even
    return (unsigned short)(u >> 16);
}

// ---------- constants ----------
// B=2, T=2048, D_MODEL=1024, H=16, KVH=4, DK=64, QKV rows=1536, total W rows=2560

// ---------- 1. fp32 -> bf16 cast for x and qkvo ----------
__global__ __launch_bounds__(256) void cast_kernel(const float4* __restrict__ x,
                                                   const float4* __restrict__ w,
                                                   ushort4* __restrict__ xbf,
                                                   ushort4* __restrict__ wbf) {
    int i = blockIdx.x * 256 + threadIdx.x;
    const int NX4 = 4096 * 1024 / 4;
    const int NW4 = 2560 * 1024 / 4;
    float4 v;
    ushort4* o;
    if (i < NX4) { v = x[i]; o = xbf + i; }
    else {
        int j = i - NX4;
        if (j >= NW4) return;
        v = w[j]; o = wbf + j;
    }
    ushort4 r;
    r.x = f2bf(v.x); r.y = f2bf(v.y); r.z = f2bf(v.z); r.w = f2bf(v.w);
    *o = r;
}

// ---------- 2/6. bf16 MFMA GEMM:  C[M,N] = A[M,K] * B[N,K]^T ----------
// wave computes a 64x64 tile (4x4 of 16x16x32 mfma); block = 4 waves = 128x128.
__global__ __launch_bounds__(256) void gemm_bf16(const ushort* __restrict__ A,
                                                 const ushort* __restrict__ B,
                                                 float* __restrict__ C,
                                                 int M, int N, int K) {
    int w = __builtin_amdgcn_readfirstlane((int)(threadIdx.x >> 6));
    int lane = threadIdx.x & 63;
    int qm = lane & 15, quad = lane >> 4;
    int m0 = blockIdx.x * 128 + (w & 1) * 64;
    int n0 = blockIdx.y * 128 + (w >> 1) * 64;

    f32x4 acc[4][4];
#pragma unroll
    for (int i = 0; i < 4; i++)
#pragma unroll
        for (int j = 0; j < 4; j++) acc[i][j] = (f32x4){0.f, 0.f, 0.f, 0.f};

    const ushort* Abase = A + (size_t)(m0 + qm) * K + quad * 8;
    const ushort* Bbase = B + (size_t)(n0 + qm) * K + quad * 8;

    for (int k0 = 0; k0 < K; k0 += 32) {
        bf16x8 a[4], bb[4];
#pragma unroll
        for (int mi = 0; mi < 4; mi++)
            a[mi] = *(const bf16x8*)(Abase + (size_t)mi * 16 * K + k0);
#pragma unroll
        for (int ni = 0; ni < 4; ni++)
            bb[ni] = *(const bf16x8*)(Bbase + (size_t)ni * 16 * K + k0);
#pragma unroll
        for (int mi = 0; mi < 4; mi++)
#pragma unroll
            for (int ni = 0; ni < 4; ni++)
                acc[mi][ni] = __builtin_amdgcn_mfma_f32_16x16x32_bf16(a[mi], bb[ni], acc[mi][ni], 0, 0, 0);
    }
    // C/D layout: row = 4*quad + r, col = lane&15
#pragma unroll
    for (int mi = 0; mi < 4; mi++)
#pragma unroll
        for (int ni = 0; ni < 4; ni++) {
            int row = m0 + mi * 16 + quad * 4;
            int col = n0 + ni * 16 + qm;
            float* cp = C + (size_t)row * N + col;
#pragma unroll
            for (int r = 0; r < 4; r++) cp[(size_t)r * N] = acc[mi][ni][r];
        }
}

// ---------- 3. fused RMSNorm + RoPE for Q and K ----------
// qkv fp32 [B*T, 1536]; writes Q bf16 [B,H,T,64] (scaled 1/8), K bf16 [B,KVH,T,64]
__global__ __launch_bounds__(256) void normrope_kernel(const float* __restrict__ qkv,
                                                       const float* __restrict__ qw,
                                                       const float* __restrict__ kw,
                                                       ushort* __restrict__ Q,
                                                       ushort* __restrict__ Kb) {
    int r = blockIdx.x;          // b*2048 + t
    int b = r >> 11;
    int t = r & 2047;
    int tid = threadIdx.x;
    int w = tid >> 6;            // wave in block -> head within group
    int lane = tid & 63;

    // RoPE angle for this lane's pair: i = lane>>1, inv_freq = 10000^(-2i/64)
    float inv_freq = __expf(-((float)(lane & 62) * (1.0f / 64.0f)) * 9.210340371976184f);
    float sn, cs;
    sincosf((float)t * inv_freq, &sn, &cs);

#pragma unroll
    for (int hg = 0; hg < 5; hg++) {   // hg 0..3 = Q heads, hg 4 = K heads
        int col = hg * 256 + w * 64 + lane;
        float v = qkv[(size_t)r * 1536 + col];
        float ss = v * v;
#pragma unroll
        for (int m = 1; m < 64; m <<= 1) ss += __shfl_xor(ss, m);
        float rinv = rsqrtf(ss * (1.0f / 64.0f) + 1.1920929e-7f);
        float wt = (hg < 4) ? qw[lane] : kw[lane];
        float vn = v * rinv * wt;
        float pr = __shfl_xor(vn, 1);
        // even lane: x1*cos - x2*sin ; odd lane: x1*sin + x2*cos
        float out = (lane & 1) ? fmaf(pr, sn, vn * cs) : fmaf(vn, cs, -pr * sn);
        if (hg < 4) {
            int h = hg * 4 + w;
            Q[((size_t)(b * 16 + h) * 2048 + t) * 64 + lane] = f2bf(out * 0.125f);
        } else {
            Kb[((size_t)(b * 4 + w) * 2048 + t) * 64 + lane] = f2bf(out);
        }
    }
}

// ---------- 4. V transpose:  qkv[:,1280:1536] -> VT bf16 [B,KVH,64,T] ----------
__global__ __launch_bounds__(256) void vtrans_kernel(const float* __restrict__ qkv,
                                                     ushort* __restrict__ VT) {
    __shared__ float tile[64][65];
    int bkv = blockIdx.x;        // b*4 + kvh
    int t0 = blockIdx.y * 64;
    int b = bkv >> 2;
    int kvh = bkv & 3;
    int tid = threadIdx.x;
    int c = tid & 63;
    int rr = tid >> 6;
#pragma unroll
    for (int p = 0; p < 16; p++) {
        int tl = p * 4 + rr;
        tile[tl][c] = qkv[((size_t)(b * 2048) + t0 + tl) * 1536 + 1280 + kvh * 64 + c];
    }
    __syncthreads();
#pragma unroll
    for (int p = 0; p < 16; p++) {
        int dd = p * 4 + rr;
        VT[((size_t)bkv * 64 + dd) * 2048 + t0 + c] = f2bf(tile[c][dd]);
    }
}

// ---------- 5. causal GQA flash attention (MFMA) ----------
// wave = 16 q-rows; block = 4 waves = 64 q-rows of one (b,h); chunks of 64 keys.
// Q pre-scaled by 1/sqrt(64). Output O bf16 [B*T, 1024] (row = b*2048+t, col = h*64+d).
__global__ __launch_bounds__(256) void attn_kernel(const ushort* __restrict__ Q,
                                                   const ushort* __restrict__ Kb,
                                                   const ushort* __restrict__ VT,
                                                   ushort* __restrict__ O) {
    __shared__ __align__(16) ushort plds[4][16][72];   // per-wave P tile, padded stride
    int blk = blockIdx.x;
    int bh = blk >> 5;                // / (2048/64)
    int q0b = (blk & 31) * 64;
    int b = bh >> 4;
    int h = bh & 15;
    int kvh = h >> 2;
    int tid = threadIdx.x;
    int w = __builtin_amdgcn_readfirstlane((int)(tid >> 6));
    int lane = tid & 63;
    int qm = lane & 15;
    int quad = lane >> 4;
    int q0w = q0b + w * 16;

    // Q A-frags (reused over all chunks): m = lane&15 -> q-row, k = d
    const ushort* qptr = Q + ((size_t)bh * 2048 + q0w + qm) * 64 + quad * 8;
    bf16x8 qa0 = *(const bf16x8*)(qptr);
    bf16x8 qa1 = *(const bf16x8*)(qptr + 32);

    const ushort* kbase = Kb + ((size_t)(b * 4 + kvh) * 2048 + qm) * 64 + quad * 8;
    const ushort* vbase = VT + ((size_t)(b * 4 + kvh) * 64 + qm) * 2048 + quad * 8;

    f32x4 oacc[4];
    float mrow[4], lrow[4];
#pragma unroll
    for (int i = 0; i < 4; i++) { oacc[i] = (f32x4){0.f, 0.f, 0.f, 0.f}; mrow[i] = -1e30f; lrow[i] = 0.f; }

    int nch = (q0b >> 6) + 1;   // uniform across the block -> barriers are safe
    for (int c0 = 0; c0 < nch; c0++) {
        int j0 = c0 * 64;
        // ---- S = Q K^T ----
        f32x4 st[4];
#pragma unroll
        for (int tj = 0; tj < 4; tj++) st[tj] = (f32x4){0.f, 0.f, 0.f, 0.f};
#pragma unroll
        for (int tj = 0; tj < 4; tj++) {
            bf16x8 kf0 = *(const bf16x8*)(kbase + (size_t)(j0 + tj * 16) * 64);
            bf16x8 kf1 = *(const bf16x8*)(kbase + (size_t)(j0 + tj * 16) * 64 + 32);
            st[tj] = __builtin_amdgcn_mfma_f32_16x16x32_bf16(qa0, kf0, st[tj], 0, 0, 0);
            st[tj] = __builtin_amdgcn_mfma_f32_16x16x32_bf16(qa1, kf1, st[tj], 0, 0, 0);
        }
        // ---- causal mask (S row = q0w + 4*quad + r, col = j0 + tj*16 + qm) ----
#pragma unroll
        for (int tj = 0; tj < 4; tj++)
#pragma unroll
            for (int r = 0; r < 4; r++) {
                int q = q0w + quad * 4 + r;
                int j = j0 + tj * 16 + qm;
                if (j > q) st[tj][r] = -1e30f;
            }
        // ---- online softmax per row ----
        float alpha[4];
#pragma unroll
        for (int r = 0; r < 4; r++) {
            float mx = fmaxf(fmaxf(st[0][r], st[1][r]), fmaxf(st[2][r], st[3][r]));
#pragma unroll
            for (int mk = 1; mk < 16; mk <<= 1) mx = fmaxf(mx, __shfl_xor(mx, mk));
            float mn = fmaxf(mrow[r], mx);
            alpha[r] = __expf(mrow[r] - mn);
            float rs = 0.f;
#pragma unroll
            for (int tj = 0; tj < 4; tj++) {
                float p = __expf(st[tj][r] - mn);
                st[tj][r] = p;
                rs += p;
            }
#pragma unroll
            for (int mk = 1; mk < 16; mk <<= 1) rs += __shfl_xor(rs, mk);
            lrow[r] = lrow[r] * alpha[r] + rs;
            mrow[r] = mn;
        }
#pragma unroll
        for (int dt = 0; dt < 4; dt++)
#pragma unroll
            for (int r = 0; r < 4; r++) oacc[dt][r] *= alpha[r];

        // ---- P: C-layout -> A-layout via LDS ----
        __syncthreads();   // protect WAR vs previous chunk's reads
#pragma unroll
        for (int tj = 0; tj < 4; tj++)
#pragma unroll
            for (int r = 0; r < 4; r++)
                plds[w][quad * 4 + r][tj * 16 + qm] = f2bf(st[tj][r]);
        __syncthreads();

        // ---- O += P V ----
#pragma unroll
        for (int win = 0; win < 2; win++) {
            bf16x8 pa = *(const bf16x8*)(&plds[w][qm][win * 32 + quad * 8]);
#pragma unroll
            for (int dt = 0; dt < 4; dt++) {
                bf16x8 vf = *(const bf16x8*)(vbase + (size_t)(dt * 16) * 2048 + j0 + win * 32);
                oacc[dt] = __builtin_amdgcn_mfma_f32_16x16x32_bf16(pa, vf, oacc[dt], 0, 0, 0);
            }
        }
    }
    // ---- epilogue ----
#pragma unroll
    for (int dt = 0; dt < 4; dt++)
#pragma unroll
        for (int r = 0; r < 4; r++) {
            int q = q0w + quad * 4 + r;
            int d = dt * 16 + qm;
            float val = oacc[dt][r] / lrow[r];
            O[((size_t)(b * 2048) + q) * 1024 + h * 64 + d] = f2bf(val);
        }
}

// ---------- launch ----------
extern "C" void kernel_launch(void* const* d_in, const int* in_sizes, int n_in,
                              void* d_out, int out_size, void* d_ws, size_t ws_size,
                              hipStream_t stream) {
    (void)in_sizes; (void)n_in; (void)out_size; (void)ws_size;
    const float* x    = (const float*)d_in[0];
    const float* qkvo = (const float*)d_in[1];
    const float* qw   = (const float*)d_in[2];
    const float* kw   = (const float*)d_in[3];
    float* out = (float*)d_out;

    char* ws = (char*)d_ws;
    ushort* xbf = (ushort*)(ws + 0);          //  8388608 B : x bf16 [4096,1024]
    ushort* wbf = (ushort*)(ws + 8388608);    //  5242880 B : qkvo bf16 [2560,1024]
    float*  qkv = (float*)(ws + 13631488);    // 25165824 B : qkv fp32 [4096,1536]
    ushort* Qb  = (ushort*)(ws + 38797312);   //  8388608 B : Q bf16 [B,H,T,64]
    ushort* Kb  = (ushort*)(ws + 47185920);   //  2097152 B : K bf16 [B,KVH,T,64]
    ushort* VT  = (ushort*)(ws + 49283072);   //  2097152 B : V^T bf16 [B,KVH,64,T]
    ushort* Ob  = (ushort*)(ws + 51380224);   //  8388608 B : attn out bf16 [4096,1024]

    cast_kernel<<<6656, 256, 0, stream>>>((const float4*)x, (const float4*)qkvo,
                                          (ushort4*)xbf, (ushort4*)wbf);
    gemm_bf16<<<dim3(32, 12), 256, 0, stream>>>(xbf, wbf, qkv, 4096, 1536, 1024);
    normrope_kernel<<<4096, 256, 0, stream>>>(qkv, qw, kw, Qb, Kb);
    vtrans_kernel<<<dim3(8, 32), 256, 0, stream>>>(qkv, VT);
    attn_kernel<<<1024, 256, 0, stream>>>(Qb, Kb, VT, Ob);
    gemm_bf16<<<dim3(32, 8), 256, 0, stream>>>(Ob, wbf + (size_t)1536 * 1024, out, 4096, 1024, 1024);
}

// Round 2
// 316.743 us; speedup vs baseline: 1.4543x; 1.4543x over previous
//
#include <hip/hip_runtime.h>
#include <hip/hip_bf16.h>
#include <cstdint>
#include <cstddef>

// ---------- types ----------
typedef __bf16 bf16x8 __attribute__((ext_vector_type(8)));
typedef float f32x4 __attribute__((ext_vector_type(4)));

__device__ __forceinline__ unsigned short f2bf(float f) {
    unsigned u = __builtin_bit_cast(unsigned, f);
    u += 0x7FFFu + ((u >> 16) & 1u);   // round-to-nearest-even
    return (unsigned short)(u >> 16);
}

// ---------- 1. fp32 -> bf16 cast for x and qkvo ----------
__global__ __launch_bounds__(256) void cast_kernel(const float4* __restrict__ x,
                                                   const float4* __restrict__ w,
                                                   ushort4* __restrict__ xbf,
                                                   ushort4* __restrict__ wbf) {
    int i = blockIdx.x * 256 + threadIdx.x;
    const int NX4 = 4096 * 1024 / 4;
    const int NW4 = 2560 * 1024 / 4;
    float4 v;
    ushort4* o;
    if (i < NX4) { v = x[i]; o = xbf + i; }
    else {
        int j = i - NX4;
        if (j >= NW4) return;
        v = w[j]; o = wbf + j;
    }
    ushort4 r;
    r.x = f2bf(v.x); r.y = f2bf(v.y); r.z = f2bf(v.z); r.w = f2bf(v.w);
    *o = r;
}

// ---------- 2/6. bf16 MFMA GEMM:  C[M,N] = A[M,K] * B[N,K]^T ----------
__global__ __launch_bounds__(256) void gemm_bf16(const ushort* __restrict__ A,
                                                 const ushort* __restrict__ B,
                                                 float* __restrict__ C,
                                                 int M, int N, int K) {
    int w = __builtin_amdgcn_readfirstlane((int)(threadIdx.x >> 6));
    int lane = threadIdx.x & 63;
    int qm = lane & 15, quad = lane >> 4;
    int m0 = blockIdx.x * 128 + (w & 1) * 64;
    int n0 = blockIdx.y * 128 + (w >> 1) * 64;

    f32x4 acc[4][4];
#pragma unroll
    for (int i = 0; i < 4; i++)
#pragma unroll
        for (int j = 0; j < 4; j++) acc[i][j] = (f32x4){0.f, 0.f, 0.f, 0.f};

    const ushort* Abase = A + (size_t)(m0 + qm) * K + quad * 8;
    const ushort* Bbase = B + (size_t)(n0 + qm) * K + quad * 8;

    for (int k0 = 0; k0 < K; k0 += 32) {
        bf16x8 a[4], bb[4];
#pragma unroll
        for (int mi = 0; mi < 4; mi++)
            a[mi] = *(const bf16x8*)(Abase + (size_t)mi * 16 * K + k0);
#pragma unroll
        for (int ni = 0; ni < 4; ni++)
            bb[ni] = *(const bf16x8*)(Bbase + (size_t)ni * 16 * K + k0);
#pragma unroll
        for (int mi = 0; mi < 4; mi++)
#pragma unroll
            for (int ni = 0; ni < 4; ni++)
                acc[mi][ni] = __builtin_amdgcn_mfma_f32_16x16x32_bf16(a[mi], bb[ni], acc[mi][ni], 0, 0, 0);
    }
#pragma unroll
    for (int mi = 0; mi < 4; mi++)
#pragma unroll
        for (int ni = 0; ni < 4; ni++) {
            int row = m0 + mi * 16 + quad * 4;
            int col = n0 + ni * 16 + qm;
            float* cp = C + (size_t)row * N + col;
#pragma unroll
            for (int r = 0; r < 4; r++) cp[(size_t)r * N] = acc[mi][ni][r];
        }
}

// ---------- 3. fused RMSNorm + RoPE for Q and K ----------
__global__ __launch_bounds__(256) void normrope_kernel(const float* __restrict__ qkv,
                                                       const float* __restrict__ qw,
                                                       const float* __restrict__ kw,
                                                       ushort* __restrict__ Q,
                                                       ushort* __restrict__ Kb) {
    int r = blockIdx.x;          // b*2048 + t
    int b = r >> 11;
    int t = r & 2047;
    int tid = threadIdx.x;
    int w = tid >> 6;
    int lane = tid & 63;

    float inv_freq = __expf(-((float)(lane & 62) * (1.0f / 64.0f)) * 9.210340371976184f);
    float sn, cs;
    sincosf((float)t * inv_freq, &sn, &cs);

#pragma unroll
    for (int hg = 0; hg < 5; hg++) {
        int col = hg * 256 + w * 64 + lane;
        float v = qkv[(size_t)r * 1536 + col];
        float ss = v * v;
#pragma unroll
        for (int m = 1; m < 64; m <<= 1) ss += __shfl_xor(ss, m);
        float rinv = rsqrtf(ss * (1.0f / 64.0f) + 1.1920929e-7f);
        float wt = (hg < 4) ? qw[lane] : kw[lane];
        float vn = v * rinv * wt;
        float pr = __shfl_xor(vn, 1);
        float out = (lane & 1) ? fmaf(pr, sn, vn * cs) : fmaf(vn, cs, -pr * sn);
        if (hg < 4) {
            int h = hg * 4 + w;
            Q[((size_t)(b * 16 + h) * 2048 + t) * 64 + lane] = f2bf(out * 0.125f);
        } else {
            Kb[((size_t)(b * 4 + w) * 2048 + t) * 64 + lane] = f2bf(out);
        }
    }
}

// ---------- 4. V transpose ----------
__global__ __launch_bounds__(256) void vtrans_kernel(const float* __restrict__ qkv,
                                                     ushort* __restrict__ VT) {
    __shared__ float tile[64][65];
    int bkv = blockIdx.x;
    int t0 = blockIdx.y * 64;
    int b = bkv >> 2;
    int kvh = bkv & 3;
    int tid = threadIdx.x;
    int c = tid & 63;
    int rr = tid >> 6;
#pragma unroll
    for (int p = 0; p < 16; p++) {
        int tl = p * 4 + rr;
        tile[tl][c] = qkv[((size_t)(b * 2048) + t0 + tl) * 1536 + 1280 + kvh * 64 + c];
    }
    __syncthreads();
#pragma unroll
    for (int p = 0; p < 16; p++) {
        int dd = p * 4 + rr;
        VT[((size_t)bkv * 64 + dd) * 2048 + t0 + c] = f2bf(tile[c][dd]);
    }
}

// ---------- 5. causal GQA flash attention v2: S-transposed, barrier-free ----------
// Each WAVE processes two paired 16-row q-tiles {p, 127-p} -> exactly 33 chunk-units
// for every wave. No __syncthreads anywhere; P^T staged in a per-wave LDS buffer.
// S^T = K·Q^T (keys on the M/row axis -> softmax reduce = in-lane + 2 shuffles).
// O^T = V^T·P^T. Q pre-scaled by 1/8. O bf16 [B*T, 1024].
__global__ __launch_bounds__(256) void attn2_kernel(const ushort* __restrict__ Q,
                                                    const ushort* __restrict__ K,
                                                    const ushort* __restrict__ VT,
                                                    ushort* __restrict__ O) {
    __shared__ __align__(16) ushort PB[4][16][80];   // per-wave P^T tile [q][key], stride 80 for 16B-aligned b128
    int blk = blockIdx.x;
    int bh = blk >> 4;                 // 0..31
    int jj = blk & 15;
    int tid = threadIdx.x;
    int w = tid >> 6;
    int lane = tid & 63;
    int qm = lane & 15, quad = lane >> 4;
    int b = bh >> 4, h = bh & 15;
    int bkv = b * 4 + (h >> 2);
    int p = jj * 4 + w;                // pair index 0..63

    ushort (*pb)[80] = PB[w];
    const ushort* Qbh = Q + (size_t)bh * 2048 * 64;
    const ushort* Kbh = K + (size_t)bkv * 2048 * 64;
    const ushort* Vbh = VT + (size_t)bkv * 64 * 2048;

#pragma unroll
    for (int t = 0; t < 2; t++) {
        int qt = (t == 0) ? p : (127 - p);
        int q0 = qt * 16;
        const ushort* qptr = Qbh + (size_t)(q0 + qm) * 64 + quad * 8;
        bf16x8 qb0 = *(const bf16x8*)qptr;        // B-operand: n=q, k=d
        bf16x8 qb1 = *(const bf16x8*)(qptr + 32);

        f32x4 oacc[4];
        float m = -1e30f, l = 0.f;
#pragma unroll
        for (int i = 0; i < 4; i++) oacc[i] = (f32x4){0.f, 0.f, 0.f, 0.f};

        int nch = (qt >> 2) + 1;
        for (int c = 0; c < nch; c++) {
            int j0 = c * 64;
            // ---- S^T = K Q^T : A = K rows (keys), B = Q ----
            f32x4 st[4];
#pragma unroll
            for (int tj = 0; tj < 4; tj++) st[tj] = (f32x4){0.f, 0.f, 0.f, 0.f};
            const ushort* kc = Kbh + (size_t)(j0 + qm) * 64 + quad * 8;
#pragma unroll
            for (int tj = 0; tj < 4; tj++) {
                bf16x8 kf0 = *(const bf16x8*)(kc + (size_t)tj * 16 * 64);
                bf16x8 kf1 = *(const bf16x8*)(kc + (size_t)tj * 16 * 64 + 32);
                st[tj] = __builtin_amdgcn_mfma_f32_16x16x32_bf16(kf0, qb0, st[tj], 0, 0, 0);
                st[tj] = __builtin_amdgcn_mfma_f32_16x16x32_bf16(kf1, qb1, st[tj], 0, 0, 0);
            }
            // st[tj][r] = S^T[key=j0+tj*16+quad*4+r][q=q0+qm]
            // ---- causal mask + in-lane max ----
            float mx = -1e30f;
#pragma unroll
            for (int tj = 0; tj < 4; tj++)
#pragma unroll
                for (int r = 0; r < 4; r++) {
                    int key = j0 + tj * 16 + quad * 4 + r;
                    if (key > q0 + qm) st[tj][r] = -1e30f;
                    mx = fmaxf(mx, st[tj][r]);
                }
            mx = fmaxf(mx, __shfl_xor(mx, 16));
            mx = fmaxf(mx, __shfl_xor(mx, 32));
            float mn = fmaxf(m, mx);
            float alpha = __expf(m - mn);
            m = mn;
            float rs = 0.f;
#pragma unroll
            for (int tj = 0; tj < 4; tj++)
#pragma unroll
                for (int r = 0; r < 4; r++) {
                    float pv = __expf(st[tj][r] - mn);
                    st[tj][r] = pv;
                    rs += pv;
                }
            rs += __shfl_xor(rs, 16);
            rs += __shfl_xor(rs, 32);
            l = l * alpha + rs;
#pragma unroll
            for (int dt = 0; dt < 4; dt++)
#pragma unroll
                for (int r = 0; r < 4; r++) oacc[dt][r] *= alpha;

            // ---- pack P^T into per-wave LDS [q][key] (bf16) ----
#pragma unroll
            for (int tj = 0; tj < 4; tj++) {
                unsigned lo = (unsigned)f2bf(st[tj][0]) | ((unsigned)f2bf(st[tj][1]) << 16);
                unsigned hi = (unsigned)f2bf(st[tj][2]) | ((unsigned)f2bf(st[tj][3]) << 16);
                uint2 val; val.x = lo; val.y = hi;
                *(uint2*)&pb[qm][tj * 16 + quad * 4] = val;
            }
            asm volatile("s_waitcnt lgkmcnt(0)" ::: "memory");   // wave-level fence (no barrier)

            // ---- O^T += V^T P^T ----
#pragma unroll
            for (int half = 0; half < 2; half++) {
                bf16x8 pfrag = *(const bf16x8*)&pb[qm][half * 32 + quad * 8];  // B: n=q, k=key
#pragma unroll
                for (int dt = 0; dt < 4; dt++) {
                    bf16x8 vf = *(const bf16x8*)(Vbh + (size_t)(dt * 16 + qm) * 2048 + j0 + half * 32 + quad * 8);
                    oacc[dt] = __builtin_amdgcn_mfma_f32_16x16x32_bf16(vf, pfrag, oacc[dt], 0, 0, 0);
                }
            }
            asm volatile("s_waitcnt lgkmcnt(0)" ::: "memory");   // reads retired before next chunk's writes
        }
        // ---- epilogue: O^T layout -> O[q][d], d = dt*16+quad*4+r ----
        float rinv = 1.0f / l;
#pragma unroll
        for (int dt = 0; dt < 4; dt++) {
            unsigned lo = (unsigned)f2bf(oacc[dt][0] * rinv) | ((unsigned)f2bf(oacc[dt][1] * rinv) << 16);
            unsigned hi = (unsigned)f2bf(oacc[dt][2] * rinv) | ((unsigned)f2bf(oacc[dt][3] * rinv) << 16);
            uint2 val; val.x = lo; val.y = hi;
            *(uint2*)&O[((size_t)(b * 2048) + q0 + qm) * 1024 + h * 64 + dt * 16 + quad * 4] = val;
        }
    }
}

// ---------- launch ----------
extern "C" void kernel_launch(void* const* d_in, const int* in_sizes, int n_in,
                              void* d_out, int out_size, void* d_ws, size_t ws_size,
                              hipStream_t stream) {
    (void)in_sizes; (void)n_in; (void)out_size; (void)ws_size;
    const float* x    = (const float*)d_in[0];
    const float* qkvo = (const float*)d_in[1];
    const float* qw   = (const float*)d_in[2];
    const float* kw   = (const float*)d_in[3];
    float* out = (float*)d_out;

    char* ws = (char*)d_ws;
    ushort* xbf = (ushort*)(ws + 0);          //  8388608 B
    ushort* wbf = (ushort*)(ws + 8388608);    //  5242880 B
    float*  qkv = (float*)(ws + 13631488);    // 25165824 B
    ushort* Qb  = (ushort*)(ws + 38797312);   //  8388608 B
    ushort* Kb  = (ushort*)(ws + 47185920);   //  2097152 B
    ushort* VT  = (ushort*)(ws + 49283072);   //  2097152 B
    ushort* Ob  = (ushort*)(ws + 51380224);   //  8388608 B

    cast_kernel<<<6656, 256, 0, stream>>>((const float4*)x, (const float4*)qkvo,
                                          (ushort4*)xbf, (ushort4*)wbf);
    gemm_bf16<<<dim3(32, 12), 256, 0, stream>>>(xbf, wbf, qkv, 4096, 1536, 1024);
    normrope_kernel<<<4096, 256, 0, stream>>>(qkv, qw, kw, Qb, Kb);
    vtrans_kernel<<<dim3(8, 32), 256, 0, stream>>>(qkv, VT);
    attn2_kernel<<<512, 256, 0, stream>>>(Qb, Kb, VT, Ob);
    gemm_bf16<<<dim3(32, 8), 256, 0, stream>>>(Ob, wbf + (size_t)1536 * 1024, out, 4096, 1024, 1024);
}

// Round 4
// 308.145 us; speedup vs baseline: 1.4949x; 1.0279x over previous
//
#include <hip/hip_runtime.h>
#include <hip/hip_bf16.h>
#include <cstdint>
#include <cstddef>

// ---------- types ----------
typedef __bf16 bf16x8 __attribute__((ext_vector_type(8)));
typedef float f32x4 __attribute__((ext_vector_type(4)));

__device__ __forceinline__ unsigned short f2bf(float f) {
    unsigned u = __builtin_bit_cast(unsigned, f);
    u += 0x7FFFu + ((u >> 16) & 1u);   // round-to-nearest-even
    return (unsigned short)(u >> 16);
}

// packed f32x2 -> bf16x2 (RTNE)
__device__ __forceinline__ unsigned pk2(float a, float b) {
    return (unsigned)f2bf(a) | ((unsigned)f2bf(b) << 16);
}

// ---------- 1. fp32 -> bf16 cast for x and qkvo ----------
__global__ __launch_bounds__(256) void cast_kernel(const float4* __restrict__ x,
                                                   const float4* __restrict__ w,
                                                   ushort4* __restrict__ xbf,
                                                   ushort4* __restrict__ wbf) {
    int i = blockIdx.x * 256 + threadIdx.x;
    const int NX4 = 4096 * 1024 / 4;
    const int NW4 = 2560 * 1024 / 4;
    float4 v;
    ushort4* o;
    if (i < NX4) { v = x[i]; o = xbf + i; }
    else {
        int j = i - NX4;
        if (j >= NW4) return;
        v = w[j]; o = wbf + j;
    }
    ushort4 r;
    r.x = f2bf(v.x); r.y = f2bf(v.y); r.z = f2bf(v.z); r.w = f2bf(v.w);
    *o = r;
}

// ---------- 2/6. bf16 MFMA GEMM:  C[M,N] = A[M,K] * B[N,K]^T ----------
__global__ __launch_bounds__(256) void gemm_bf16(const ushort* __restrict__ A,
                                                 const ushort* __restrict__ B,
                                                 float* __restrict__ C,
                                                 int M, int N, int K) {
    int w = __builtin_amdgcn_readfirstlane((int)(threadIdx.x >> 6));
    int lane = threadIdx.x & 63;
    int qm = lane & 15, quad = lane >> 4;
    int m0 = blockIdx.x * 128 + (w & 1) * 64;
    int n0 = blockIdx.y * 128 + (w >> 1) * 64;

    f32x4 acc[4][4];
#pragma unroll
    for (int i = 0; i < 4; i++)
#pragma unroll
        for (int j = 0; j < 4; j++) acc[i][j] = (f32x4){0.f, 0.f, 0.f, 0.f};

    const ushort* Abase = A + (size_t)(m0 + qm) * K + quad * 8;
    const ushort* Bbase = B + (size_t)(n0 + qm) * K + quad * 8;

    for (int k0 = 0; k0 < K; k0 += 32) {
        bf16x8 a[4], bb[4];
#pragma unroll
        for (int mi = 0; mi < 4; mi++)
            a[mi] = *(const bf16x8*)(Abase + (size_t)mi * 16 * K + k0);
#pragma unroll
        for (int ni = 0; ni < 4; ni++)
            bb[ni] = *(const bf16x8*)(Bbase + (size_t)ni * 16 * K + k0);
#pragma unroll
        for (int mi = 0; mi < 4; mi++)
#pragma unroll
            for (int ni = 0; ni < 4; ni++)
                acc[mi][ni] = __builtin_amdgcn_mfma_f32_16x16x32_bf16(a[mi], bb[ni], acc[mi][ni], 0, 0, 0);
    }
#pragma unroll
    for (int mi = 0; mi < 4; mi++)
#pragma unroll
        for (int ni = 0; ni < 4; ni++) {
            int row = m0 + mi * 16 + quad * 4;
            int col = n0 + ni * 16 + qm;
            float* cp = C + (size_t)row * N + col;
#pragma unroll
            for (int r = 0; r < 4; r++) cp[(size_t)r * N] = acc[mi][ni][r];
        }
}

// ---------- 3. fused RMSNorm + RoPE for Q and K ----------
__global__ __launch_bounds__(256) void normrope_kernel(const float* __restrict__ qkv,
                                                       const float* __restrict__ qw,
                                                       const float* __restrict__ kw,
                                                       ushort* __restrict__ Q,
                                                       ushort* __restrict__ Kb) {
    int r = blockIdx.x;          // b*2048 + t
    int b = r >> 11;
    int t = r & 2047;
    int tid = threadIdx.x;
    int w = tid >> 6;
    int lane = tid & 63;

    float inv_freq = __expf(-((float)(lane & 62) * (1.0f / 64.0f)) * 9.210340371976184f);
    float sn, cs;
    sincosf((float)t * inv_freq, &sn, &cs);

#pragma unroll
    for (int hg = 0; hg < 5; hg++) {
        int col = hg * 256 + w * 64 + lane;
        float v = qkv[(size_t)r * 1536 + col];
        float ss = v * v;
#pragma unroll
        for (int m = 1; m < 64; m <<= 1) ss += __shfl_xor(ss, m);
        float rinv = rsqrtf(ss * (1.0f / 64.0f) + 1.1920929e-7f);
        float wt = (hg < 4) ? qw[lane] : kw[lane];
        float vn = v * rinv * wt;
        float pr = __shfl_xor(vn, 1);
        float out = (lane & 1) ? fmaf(pr, sn, vn * cs) : fmaf(vn, cs, -pr * sn);
        if (hg < 4) {
            int h = hg * 4 + w;
            Q[((size_t)(b * 16 + h) * 2048 + t) * 64 + lane] = f2bf(out * 0.125f);
        } else {
            Kb[((size_t)(b * 4 + w) * 2048 + t) * 64 + lane] = f2bf(out);
        }
    }
}

// ---------- 4. V transpose ----------
__global__ __launch_bounds__(256) void vtrans_kernel(const float* __restrict__ qkv,
                                                     ushort* __restrict__ VT) {
    __shared__ float tile[64][65];
    int bkv = blockIdx.x;
    int t0 = blockIdx.y * 64;
    int b = bkv >> 2;
    int kvh = bkv & 3;
    int tid = threadIdx.x;
    int c = tid & 63;
    int rr = tid >> 6;
#pragma unroll
    for (int p = 0; p < 16; p++) {
        int tl = p * 4 + rr;
        tile[tl][c] = qkv[((size_t)(b * 2048) + t0 + tl) * 1536 + 1280 + kvh * 64 + c];
    }
    __syncthreads();
#pragma unroll
    for (int p = 0; p < 16; p++) {
        int dd = p * 4 + rr;
        VT[((size_t)bkv * 64 + dd) * 2048 + t0 + c] = f2bf(tile[c][dd]);
    }
}

// ---------- 5. attn v3: split-K across the 4 waves of a block ----------
// Block = q-tile pair {p, 127-p} of one (b,h): 33 chunk-units total, uniform.
// Wave w takes chunks c = w, w+4, ... with private online softmax; per-tile
// merge of 4 partials (m,l,O^T) through LDS. S^T = K*Q^T, O^T = V^T*P^T.
// Q pre-scaled 1/8. Mask only on the last chunk (wave-uniform branch).
__global__ __launch_bounds__(256) void attn3_kernel(const ushort* __restrict__ Q,
                                                    const ushort* __restrict__ K,
                                                    const ushort* __restrict__ VT,
                                                    ushort* __restrict__ O) {
    // SMEM layout: [0,16384) f32x4 OP[16][64]  (index (dt*4+w)*64+lane)
    //              [16384,16896) float ML[4][16][2]
    // P-staging PB[w] = 16x80 ushorts at SMEM + w*2560 — ALIASES OP, lifetimes
    // separated by __syncthreads().
    __shared__ __align__(16) char SMEM[16896];
    f32x4* OP = (f32x4*)SMEM;
    float* ML = (float*)(SMEM + 16384);

    int blk = blockIdx.x;
    int bh = blk >> 6;                 // 0..31
    int p  = blk & 63;                 // pair index
    int tid = threadIdx.x;
    int w = tid >> 6;
    int lane = tid & 63;
    int qm = lane & 15, quad = lane >> 4;
    int b = bh >> 4, h = bh & 15;
    int bkv = b * 4 + (h >> 2);
    ushort (*pb)[80] = (ushort(*)[80])(SMEM + w * 2560);

    const ushort* Qbh = Q + (size_t)bh * 2048 * 64;
    const ushort* Kbh = K + (size_t)bkv * 2048 * 64;
    const ushort* Vbh = VT + (size_t)bkv * 64 * 2048;

#pragma unroll 1
    for (int t = 0; t < 2; t++) {
        int qt = t ? (127 - p) : p;
        int q0 = qt * 16;
        int nch = (qt >> 2) + 1;
        const ushort* qptr = Qbh + (size_t)(q0 + qm) * 64 + quad * 8;
        bf16x8 qb0 = *(const bf16x8*)qptr;        // B-operand: n=q, k=d
        bf16x8 qb1 = *(const bf16x8*)(qptr + 32);

        f32x4 oacc[4];
        float m = -1e30f, l = 0.f;
#pragma unroll
        for (int i = 0; i < 4; i++) oacc[i] = (f32x4){0.f, 0.f, 0.f, 0.f};

        for (int c = w; c < nch; c += 4) {
            int j0 = c * 64;
            // ---- S^T = K Q^T ----
            f32x4 st[4];
#pragma unroll
            for (int tj = 0; tj < 4; tj++) st[tj] = (f32x4){0.f, 0.f, 0.f, 0.f};
            const ushort* kc = Kbh + (size_t)(j0 + qm) * 64 + quad * 8;
#pragma unroll
            for (int tj = 0; tj < 4; tj++) {
                bf16x8 kf0 = *(const bf16x8*)(kc + (size_t)tj * 16 * 64);
                bf16x8 kf1 = *(const bf16x8*)(kc + (size_t)tj * 16 * 64 + 32);
                st[tj] = __builtin_amdgcn_mfma_f32_16x16x32_bf16(kf0, qb0, st[tj], 0, 0, 0);
                st[tj] = __builtin_amdgcn_mfma_f32_16x16x32_bf16(kf1, qb1, st[tj], 0, 0, 0);
            }
            // st[tj][r] = S^T[key = j0+tj*16+quad*4+r][q = q0+qm]
            if (c == nch - 1) {        // only the diagonal chunk needs the mask
#pragma unroll
                for (int tj = 0; tj < 4; tj++)
#pragma unroll
                    for (int r = 0; r < 4; r++) {
                        int key = j0 + tj * 16 + quad * 4 + r;
                        if (key > q0 + qm) st[tj][r] = -1e30f;
                    }
            }
            // ---- online softmax (keys in-lane + across quads) ----
            float mx = st[0][0];
#pragma unroll
            for (int tj = 0; tj < 4; tj++)
#pragma unroll
                for (int r = 0; r < 4; r++) mx = fmaxf(mx, st[tj][r]);
            mx = fmaxf(mx, __shfl_xor(mx, 16));
            mx = fmaxf(mx, __shfl_xor(mx, 32));
            float mn = fmaxf(m, mx);
            float alpha = __expf(m - mn);
            m = mn;
            float rs = 0.f;
#pragma unroll
            for (int tj = 0; tj < 4; tj++)
#pragma unroll
                for (int r = 0; r < 4; r++) {
                    float pv = __expf(st[tj][r] - mn);
                    st[tj][r] = pv;
                    rs += pv;
                }
            rs += __shfl_xor(rs, 16);
            rs += __shfl_xor(rs, 32);
            l = l * alpha + rs;
#pragma unroll
            for (int dt = 0; dt < 4; dt++)
#pragma unroll
                for (int r = 0; r < 4; r++) oacc[dt][r] *= alpha;

            // ---- pack P^T into per-wave LDS [q][key] ----
#pragma unroll
            for (int tj = 0; tj < 4; tj++) {
                uint2 val;
                val.x = pk2(st[tj][0], st[tj][1]);
                val.y = pk2(st[tj][2], st[tj][3]);
                *(uint2*)&pb[qm][tj * 16 + quad * 4] = val;
            }
            asm volatile("s_waitcnt lgkmcnt(0)" ::: "memory");

            // ---- O^T += V^T P^T ----
#pragma unroll
            for (int half = 0; half < 2; half++) {
                bf16x8 pfrag = *(const bf16x8*)&pb[qm][half * 32 + quad * 8];
#pragma unroll
                for (int dt = 0; dt < 4; dt++) {
                    bf16x8 vf = *(const bf16x8*)(Vbh + (size_t)(dt * 16 + qm) * 2048 + j0 + half * 32 + quad * 8);
                    oacc[dt] = __builtin_amdgcn_mfma_f32_16x16x32_bf16(vf, pfrag, oacc[dt], 0, 0, 0);
                }
            }
            asm volatile("s_waitcnt lgkmcnt(0)" ::: "memory");
        }

        // ---- merge the 4 wave-partials ----
        __syncthreads();                       // all PB use done (PB aliases OP)
#pragma unroll
        for (int dt = 0; dt < 4; dt++)
            OP[(dt * 4 + w) * 64 + lane] = oacc[dt];
        ML[(w * 16 + qm) * 2]     = m;         // quads write same value: benign
        ML[(w * 16 + qm) * 2 + 1] = l;
        __syncthreads();

        float m0 = ML[(0 * 16 + qm) * 2], l0 = ML[(0 * 16 + qm) * 2 + 1];
        float m1 = ML[(1 * 16 + qm) * 2], l1 = ML[(1 * 16 + qm) * 2 + 1];
        float m2 = ML[(2 * 16 + qm) * 2], l2 = ML[(2 * 16 + qm) * 2 + 1];
        float m3 = ML[(3 * 16 + qm) * 2], l3 = ML[(3 * 16 + qm) * 2 + 1];
        float ms = fmaxf(fmaxf(m0, m1), fmaxf(m2, m3));
        float c0 = __expf(m0 - ms), c1 = __expf(m1 - ms);
        float c2 = __expf(m2 - ms), c3 = __expf(m3 - ms);
        float lstar = c0 * l0 + c1 * l1 + c2 * l2 + c3 * l3;
        // wave w reduces its own dt = w slice
        f32x4 a0 = OP[(w * 4 + 0) * 64 + lane];
        f32x4 a1 = OP[(w * 4 + 1) * 64 + lane];
        f32x4 a2 = OP[(w * 4 + 2) * 64 + lane];
        f32x4 a3 = OP[(w * 4 + 3) * 64 + lane];
        f32x4 fin;
#pragma unroll
        for (int r = 0; r < 4; r++)
            fin[r] = c0 * a0[r] + c1 * a1[r] + c2 * a2[r] + c3 * a3[r];
        float rinv = 1.0f / lstar;
        uint2 val;
        val.x = pk2(fin[0] * rinv, fin[1] * rinv);
        val.y = pk2(fin[2] * rinv, fin[3] * rinv);
        *(uint2*)&O[((size_t)(b * 2048) + q0 + qm) * 1024 + h * 64 + w * 16 + quad * 4] = val;
        __syncthreads();                       // merge reads done before next tile's PB writes
    }
}

// ---------- launch ----------
extern "C" void kernel_launch(void* const* d_in, const int* in_sizes, int n_in,
                              void* d_out, int out_size, void* d_ws, size_t ws_size,
                              hipStream_t stream) {
    (void)in_sizes; (void)n_in; (void)out_size; (void)ws_size;
    const float* x    = (const float*)d_in[0];
    const float* qkvo = (const float*)d_in[1];
    const float* qw   = (const float*)d_in[2];
    const float* kw   = (const float*)d_in[3];
    float* out = (float*)d_out;

    char* ws = (char*)d_ws;
    ushort* xbf = (ushort*)(ws + 0);          //  8388608 B
    ushort* wbf = (ushort*)(ws + 8388608);    //  5242880 B
    float*  qkv = (float*)(ws + 13631488);    // 25165824 B
    ushort* Qb  = (ushort*)(ws + 38797312);   //  8388608 B
    ushort* Kb  = (ushort*)(ws + 47185920);   //  2097152 B
    ushort* VT  = (ushort*)(ws + 49283072);   //  2097152 B
    ushort* Ob  = (ushort*)(ws + 51380224);   //  8388608 B

    cast_kernel<<<6656, 256, 0, stream>>>((const float4*)x, (const float4*)qkvo,
                                          (ushort4*)xbf, (ushort4*)wbf);
    gemm_bf16<<<dim3(32, 12), 256, 0, stream>>>(xbf, wbf, qkv, 4096, 1536, 1024);
    normrope_kernel<<<4096, 256, 0, stream>>>(qkv, qw, kw, Qb, Kb);
    vtrans_kernel<<<dim3(8, 32), 256, 0, stream>>>(qkv, VT);
    attn3_kernel<<<2048, 256, 0, stream>>>(Qb, Kb, VT, Ob);
    gemm_bf16<<<dim3(32, 8), 256, 0, stream>>>(Ob, wbf + (size_t)1536 * 1024, out, 4096, 1024, 1024);
}

// Round 5
// 190.236 us; speedup vs baseline: 2.4214x; 1.6198x over previous
//
#include <hip/hip_runtime.h>
#include <hip/hip_bf16.h>
#include <cstdint>
#include <cstddef>

// ---------- types ----------
typedef __bf16 bf16x8 __attribute__((ext_vector_type(8)));
typedef float f32x4 __attribute__((ext_vector_type(4)));

__device__ __forceinline__ unsigned short f2bf(float f) {
    unsigned u = __builtin_bit_cast(unsigned, f);
    u += 0x7FFFu + ((u >> 16) & 1u);   // round-to-nearest-even
    return (unsigned short)(u >> 16);
}
__device__ __forceinline__ unsigned pk2(float a, float b) {
    return (unsigned)f2bf(a) | ((unsigned)f2bf(b) << 16);
}
// async global->LDS, 16B per lane. LDS dest must be uniform-base + lane*16.
__device__ __forceinline__ void gld16(const void* g, void* l) {
    __builtin_amdgcn_global_load_lds((const __attribute__((address_space(1))) void*)g,
                                     (__attribute__((address_space(3))) void*)l, 16, 0, 0);
}

// ---------- 1. fp32 -> bf16 cast ----------
__global__ __launch_bounds__(256) void cast_kernel(const float4* __restrict__ x,
                                                   const float4* __restrict__ w,
                                                   ushort4* __restrict__ xbf,
                                                   ushort4* __restrict__ wbf) {
    int i = blockIdx.x * 256 + threadIdx.x;
    const int NX4 = 4096 * 1024 / 4;
    const int NW4 = 2560 * 1024 / 4;
    float4 v;
    ushort4* o;
    if (i < NX4) { v = x[i]; o = xbf + i; }
    else {
        int j = i - NX4;
        if (j >= NW4) return;
        v = w[j]; o = wbf + j;
    }
    ushort4 r;
    r.x = f2bf(v.x); r.y = f2bf(v.y); r.z = f2bf(v.z); r.w = f2bf(v.w);
    *o = r;
}

// ---------- 2/6. bf16 GEMM, m97 structure: LDS double-buffer + global_load_lds ----------
// C[M,N] = A[M,K] * B[N,K]^T. Block 256 thr = 128x128 tile, BK=32.
// LDS slot s (0..511): row = s>>2, kgroup = s&3 (16B each). Frag reads are
// conflict-free: bank group = 4*(4*(row&1)+quad) covers 8 groups x 8 lanes.
__global__ __launch_bounds__(256) void gemm_bf16(const ushort* __restrict__ A,
                                                 const ushort* __restrict__ B,
                                                 float* __restrict__ C,
                                                 int M, int N, int K) {
    __shared__ __align__(16) ushort LA[2][4096];   // 8KB per buf
    __shared__ __align__(16) ushort LB[2][4096];
    int tid = threadIdx.x;
    int w = tid >> 6, lane = tid & 63;
    int qm = lane & 15, quad = lane >> 4;
    int m0 = blockIdx.x * 128, n0 = blockIdx.y * 128;
    int mw = (w & 1) * 64, nw = (w >> 1) * 64;

    f32x4 acc[4][4];
#pragma unroll
    for (int i = 0; i < 4; i++)
#pragma unroll
        for (int j = 0; j < 4; j++) acc[i][j] = (f32x4){0.f, 0.f, 0.f, 0.f};

    int s0 = tid, s1 = tid + 256;
    int ar0 = s0 >> 2, ag0 = s0 & 3;
    int ar1 = s1 >> 2, ag1 = s1 & 3;

    auto do_stage = [&](int k0, int buf) {
        gld16(A + (size_t)(m0 + ar0) * K + k0 + ag0 * 8, &LA[buf][s0 * 8]);
        gld16(A + (size_t)(m0 + ar1) * K + k0 + ag1 * 8, &LA[buf][s1 * 8]);
        gld16(B + (size_t)(n0 + ar0) * K + k0 + ag0 * 8, &LB[buf][s0 * 8]);
        gld16(B + (size_t)(n0 + ar1) * K + k0 + ag1 * 8, &LB[buf][s1 * 8]);
    };

    do_stage(0, 0);
    int buf = 0;
    for (int k0 = 0; k0 < K; k0 += 32, buf ^= 1) {
        __syncthreads();                       // staged buf ready (vmcnt drain)
        if (k0 + 32 < K) do_stage(k0 + 32, buf ^ 1);
        bf16x8 a[4], bb[4];
#pragma unroll
        for (int mi = 0; mi < 4; mi++)
            a[mi] = *(const bf16x8*)&LA[buf][((mw + mi * 16 + qm) * 4 + quad) * 8];
#pragma unroll
        for (int ni = 0; ni < 4; ni++)
            bb[ni] = *(const bf16x8*)&LB[buf][((nw + ni * 16 + qm) * 4 + quad) * 8];
#pragma unroll
        for (int mi = 0; mi < 4; mi++)
#pragma unroll
            for (int ni = 0; ni < 4; ni++)
                acc[mi][ni] = __builtin_amdgcn_mfma_f32_16x16x32_bf16(a[mi], bb[ni], acc[mi][ni], 0, 0, 0);
    }
#pragma unroll
    for (int mi = 0; mi < 4; mi++)
#pragma unroll
        for (int ni = 0; ni < 4; ni++) {
            int row = m0 + mw + mi * 16 + quad * 4;
            int col = n0 + nw + ni * 16 + qm;
            float* cp = C + (size_t)row * N + col;
#pragma unroll
            for (int r = 0; r < 4; r++) cp[(size_t)r * N] = acc[mi][ni][r];
        }
}

// ---------- 3. fused RMSNorm + RoPE ----------
__global__ __launch_bounds__(256) void normrope_kernel(const float* __restrict__ qkv,
                                                       const float* __restrict__ qw,
                                                       const float* __restrict__ kw,
                                                       ushort* __restrict__ Q,
                                                       ushort* __restrict__ Kb) {
    int r = blockIdx.x;          // b*2048 + t
    int b = r >> 11;
    int t = r & 2047;
    int tid = threadIdx.x;
    int w = tid >> 6;
    int lane = tid & 63;

    float inv_freq = __expf(-((float)(lane & 62) * (1.0f / 64.0f)) * 9.210340371976184f);
    float sn, cs;
    sincosf((float)t * inv_freq, &sn, &cs);

#pragma unroll
    for (int hg = 0; hg < 5; hg++) {
        int col = hg * 256 + w * 64 + lane;
        float v = qkv[(size_t)r * 1536 + col];
        float ss = v * v;
#pragma unroll
        for (int m = 1; m < 64; m <<= 1) ss += __shfl_xor(ss, m);
        float rinv = rsqrtf(ss * (1.0f / 64.0f) + 1.1920929e-7f);
        float wt = (hg < 4) ? qw[lane] : kw[lane];
        float vn = v * rinv * wt;
        float pr = __shfl_xor(vn, 1);
        float out = (lane & 1) ? fmaf(pr, sn, vn * cs) : fmaf(vn, cs, -pr * sn);
        if (hg < 4) {
            int h = hg * 4 + w;
            Q[((size_t)(b * 16 + h) * 2048 + t) * 64 + lane] = f2bf(out * 0.125f);
        } else {
            Kb[((size_t)(b * 4 + w) * 2048 + t) * 64 + lane] = f2bf(out);
        }
    }
}

// ---------- 4. V transpose ----------
__global__ __launch_bounds__(256) void vtrans_kernel(const float* __restrict__ qkv,
                                                     ushort* __restrict__ VT) {
    __shared__ float tile[64][65];
    int bkv = blockIdx.x;
    int t0 = blockIdx.y * 64;
    int b = bkv >> 2;
    int kvh = bkv & 3;
    int tid = threadIdx.x;
    int c = tid & 63;
    int rr = tid >> 6;
#pragma unroll
    for (int p = 0; p < 16; p++) {
        int tl = p * 4 + rr;
        tile[tl][c] = qkv[((size_t)(b * 2048) + t0 + tl) * 1536 + 1280 + kvh * 64 + c];
    }
    __syncthreads();
#pragma unroll
    for (int p = 0; p < 16; p++) {
        int dd = p * 4 + rr;
        VT[((size_t)bkv * 64 + dd) * 2048 + t0 + c] = f2bf(tile[c][dd]);
    }
}

// ---------- 5. attn v4: block-staged K/V in LDS, XOR-swizzled, dbuf ----------
// Block = pair of 64-row q-blocks {p, 31-p} of one (b,h): 33 uniform 64-key
// chunks. Wave w owns q-tile (16 rows) w; all 4 waves consume the SAME staged
// K/V chunk. No split-K merge. S^T = K*Q^T, O^T = V^T*P^T, Q pre-scaled 1/8.
// Swizzle: 16B slot = row*8 + (g ^ (row&7)) -> min bank accesses for b64 w / b128 r.
__global__ __launch_bounds__(256) void attn4_kernel(const ushort* __restrict__ Q,
                                                    const ushort* __restrict__ K,
                                                    const ushort* __restrict__ VT,
                                                    ushort* __restrict__ O) {
    __shared__ __align__(16) ushort KT[2][4096];    // K chunk: 64 keys x 64 d
    __shared__ __align__(16) ushort VL[2][4096];    // V^T chunk: 64 d x 64 keys
    __shared__ __align__(16) ushort PBuf[4][1024];  // per-wave P: 16 q x 64 keys

    int blk = blockIdx.x;
    int bh = blk >> 4;                 // 0..31
    int p  = blk & 15;                 // pair index
    int tid = threadIdx.x;
    int w = tid >> 6, lane = tid & 63;
    int qm = lane & 15, quad = lane >> 4;
    int b = bh >> 4, h = bh & 15;
    int bkv = b * 4 + (h >> 2);

    const ushort* Qbh = Q + (size_t)bh * 2048 * 64;
    const ushort* Kbh = K + (size_t)bkv * 2048 * 64;
    const ushort* Vbh = VT + (size_t)bkv * 64 * 2048;
    ushort* pb = PBuf[w];
    int sw = qm & 7;                   // row-swizzle key for this lane's frag rows

    // staging slots: thread covers s and s+256; slot s -> row s>>3, g = (s&7)^((s>>3)&7)
    int s0 = tid, s1 = tid + 256;
    int r0 = s0 >> 3, g0 = (s0 & 7) ^ (r0 & 7);
    int r1 = s1 >> 3, g1 = (s1 & 7) ^ (r1 & 7);

    auto do_stage = [&](int j0, int buf) {
        gld16(Kbh + (size_t)(j0 + r0) * 64 + g0 * 8, &KT[buf][s0 * 8]);
        gld16(Kbh + (size_t)(j0 + r1) * 64 + g1 * 8, &KT[buf][s1 * 8]);
        gld16(Vbh + (size_t)r0 * 2048 + j0 + g0 * 8, &VL[buf][s0 * 8]);
        gld16(Vbh + (size_t)r1 * 2048 + j0 + g1 * 8, &VL[buf][s1 * 8]);
    };

    int qblkA = p, qblkB = 31 - p;
    int nchA = qblkA + 1;
    const int total = 33;              // nchA + nchB

    // per-wave tile state (tile A first)
    int q0 = qblkA * 64 + w * 16;
    const ushort* qptr = Qbh + (size_t)(q0 + qm) * 64 + quad * 8;
    bf16x8 qb0 = *(const bf16x8*)qptr;
    bf16x8 qb1 = *(const bf16x8*)(qptr + 32);
    f32x4 oacc[4];
    float m = -1e30f, l = 0.f;
#pragma unroll
    for (int i = 0; i < 4; i++) oacc[i] = (f32x4){0.f, 0.f, 0.f, 0.f};

    auto writeO = [&]() {
        float rinv = 1.0f / l;
        uint2 val;
#pragma unroll
        for (int dt = 0; dt < 4; dt++) {
            val.x = pk2(oacc[dt][0] * rinv, oacc[dt][1] * rinv);
            val.y = pk2(oacc[dt][2] * rinv, oacc[dt][3] * rinv);
            *(uint2*)&O[((size_t)(b * 2048) + q0 + qm) * 1024 + h * 64 + dt * 16 + quad * 4] = val;
        }
    };

    do_stage(0, 0);
    int buf = 0;
#pragma unroll 1
    for (int i = 0; i < total; i++, buf ^= 1) {
        bool inB = (i >= nchA);
        int c = inB ? i - nchA : i;
        int j0 = c * 64;
        int nch = inB ? (qblkB + 1) : nchA;

        if (i == nchA) {               // tile switch: flush A, init B
            writeO();
            q0 = qblkB * 64 + w * 16;
            const ushort* qp2 = Qbh + (size_t)(q0 + qm) * 64 + quad * 8;
            qb0 = *(const bf16x8*)qp2;
            qb1 = *(const bf16x8*)(qp2 + 32);
            m = -1e30f; l = 0.f;
#pragma unroll
            for (int ii = 0; ii < 4; ii++) oacc[ii] = (f32x4){0.f, 0.f, 0.f, 0.f};
        }

        __syncthreads();               // staged buf ready for everyone
        int ni = i + 1;
        if (ni < total) do_stage(ni < nchA ? 64 * ni : 64 * (ni - nchA), buf ^ 1);

        // ---- S^T = K Q^T from LDS ----
        f32x4 st[4];
#pragma unroll
        for (int tj = 0; tj < 4; tj++) st[tj] = (f32x4){0.f, 0.f, 0.f, 0.f};
#pragma unroll
        for (int tj = 0; tj < 4; tj++) {
            bf16x8 kf0 = *(const bf16x8*)&KT[buf][((16 * tj + qm) * 8 + (quad ^ sw)) * 8];
            bf16x8 kf1 = *(const bf16x8*)&KT[buf][((16 * tj + qm) * 8 + ((4 + quad) ^ sw)) * 8];
            st[tj] = __builtin_amdgcn_mfma_f32_16x16x32_bf16(kf0, qb0, st[tj], 0, 0, 0);
            st[tj] = __builtin_amdgcn_mfma_f32_16x16x32_bf16(kf1, qb1, st[tj], 0, 0, 0);
        }
        // st[tj][r] = S^T[key = j0+16tj+4quad+r][q = q0+qm]
        if (c == nch - 1) {            // diagonal chunk: causal mask
#pragma unroll
            for (int tj = 0; tj < 4; tj++)
#pragma unroll
                for (int r = 0; r < 4; r++) {
                    int key = j0 + tj * 16 + quad * 4 + r;
                    if (key > q0 + qm) st[tj][r] = -1e30f;
                }
        }
        // ---- online softmax ----
        float mx = st[0][0];
#pragma unroll
        for (int tj = 0; tj < 4; tj++)
#pragma unroll
            for (int r = 0; r < 4; r++) mx = fmaxf(mx, st[tj][r]);
        mx = fmaxf(mx, __shfl_xor(mx, 16));
        mx = fmaxf(mx, __shfl_xor(mx, 32));
        float mn = fmaxf(m, mx);
        float alpha = __expf(m - mn);
        m = mn;
        float rs = 0.f;
#pragma unroll
        for (int tj = 0; tj < 4; tj++)
#pragma unroll
            for (int r = 0; r < 4; r++) {
                float pv = __expf(st[tj][r] - mn);
                st[tj][r] = pv;
                rs += pv;
            }
        rs += __shfl_xor(rs, 16);
        rs += __shfl_xor(rs, 32);
        l = l * alpha + rs;
#pragma unroll
        for (int dt = 0; dt < 4; dt++)
#pragma unroll
            for (int r = 0; r < 4; r++) oacc[dt][r] *= alpha;

        // ---- pack P^T (swizzled per-wave LDS, b64 writes) ----
#pragma unroll
        for (int tj = 0; tj < 4; tj++) {
            int g = 2 * tj + (quad >> 1);
            uint2 val;
            val.x = pk2(st[tj][0], st[tj][1]);
            val.y = pk2(st[tj][2], st[tj][3]);
            *(uint2*)&pb[(qm * 8 + (g ^ sw)) * 8 + (quad & 1) * 4] = val;
        }
        asm volatile("s_waitcnt lgkmcnt(0)" ::: "memory");

        // ---- O^T += V^T P^T (both from LDS) ----
#pragma unroll
        for (int half = 0; half < 2; half++) {
            int gg = 4 * half + quad;
            bf16x8 pfrag = *(const bf16x8*)&pb[(qm * 8 + (gg ^ sw)) * 8];
#pragma unroll
            for (int dt = 0; dt < 4; dt++) {
                bf16x8 vf = *(const bf16x8*)&VL[buf][((16 * dt + qm) * 8 + (gg ^ sw)) * 8];
                oacc[dt] = __builtin_amdgcn_mfma_f32_16x16x32_bf16(vf, pfrag, oacc[dt], 0, 0, 0);
            }
        }
    }
    writeO();                          // flush tile B
}

// ---------- launch ----------
extern "C" void kernel_launch(void* const* d_in, const int* in_sizes, int n_in,
                              void* d_out, int out_size, void* d_ws, size_t ws_size,
                              hipStream_t stream) {
    (void)in_sizes; (void)n_in; (void)out_size; (void)ws_size;
    const float* x    = (const float*)d_in[0];
    const float* qkvo = (const float*)d_in[1];
    const float* qw   = (const float*)d_in[2];
    const float* kw   = (const float*)d_in[3];
    float* out = (float*)d_out;

    char* ws = (char*)d_ws;
    ushort* xbf = (ushort*)(ws + 0);          //  8388608 B
    ushort* wbf = (ushort*)(ws + 8388608);    //  5242880 B
    float*  qkv = (float*)(ws + 13631488);    // 25165824 B
    ushort* Qb  = (ushort*)(ws + 38797312);   //  8388608 B
    ushort* Kb  = (ushort*)(ws + 47185920);   //  2097152 B
    ushort* VT  = (ushort*)(ws + 49283072);   //  2097152 B
    ushort* Ob  = (ushort*)(ws + 51380224);   //  8388608 B

    cast_kernel<<<6656, 256, 0, stream>>>((const float4*)x, (const float4*)qkvo,
                                          (ushort4*)xbf, (ushort4*)wbf);
    gemm_bf16<<<dim3(32, 12), 256, 0, stream>>>(xbf, wbf, qkv, 4096, 1536, 1024);
    normrope_kernel<<<4096, 256, 0, stream>>>(qkv, qw, kw, Qb, Kb);
    vtrans_kernel<<<dim3(8, 32), 256, 0, stream>>>(qkv, VT);
    attn4_kernel<<<512, 256, 0, stream>>>(Qb, Kb, VT, Ob);
    gemm_bf16<<<dim3(32, 8), 256, 0, stream>>>(Ob, wbf + (size_t)1536 * 1024, out, 4096, 1024, 1024);
}

// Round 6
// 171.806 us; speedup vs baseline: 2.6812x; 1.1073x over previous
//
#include <hip/hip_runtime.h>
#include <hip/hip_bf16.h>
#include <cstdint>
#include <cstddef>

// ---------- types ----------
typedef __bf16 bf16x8 __attribute__((ext_vector_type(8)));
typedef float f32x4 __attribute__((ext_vector_type(4)));

__device__ __forceinline__ unsigned short f2bf(float f) {
    unsigned u = __builtin_bit_cast(unsigned, f);
    u += 0x7FFFu + ((u >> 16) & 1u);   // round-to-nearest-even
    return (unsigned short)(u >> 16);
}
// packed f32x2 -> bf16x2 via native HW convert (RTNE)
__device__ __forceinline__ unsigned pk2(float a, float b) {
    typedef __bf16 bf16x2 __attribute__((ext_vector_type(2)));
    bf16x2 h;
    h[0] = (__bf16)a;
    h[1] = (__bf16)b;
    unsigned r;
    __builtin_memcpy(&r, &h, 4);
    return r;
}
__device__ __forceinline__ float fexp2(float x) {
#if __has_builtin(__builtin_amdgcn_exp2f)
    return __builtin_amdgcn_exp2f(x);
#else
    return __expf(x * 0.6931471805599453f);
#endif
}
// async global->LDS, 16B per lane. LDS dest must be uniform-base + lane*16.
__device__ __forceinline__ void gld16(const void* g, void* l) {
    __builtin_amdgcn_global_load_lds((const __attribute__((address_space(1))) void*)g,
                                     (__attribute__((address_space(3))) void*)l, 16, 0, 0);
}

// ---------- 1. fp32 -> bf16 cast ----------
__global__ __launch_bounds__(256) void cast_kernel(const float4* __restrict__ x,
                                                   const float4* __restrict__ w,
                                                   ushort4* __restrict__ xbf,
                                                   ushort4* __restrict__ wbf) {
    int i = blockIdx.x * 256 + threadIdx.x;
    const int NX4 = 4096 * 1024 / 4;
    const int NW4 = 2560 * 1024 / 4;
    float4 v;
    ushort4* o;
    if (i < NX4) { v = x[i]; o = xbf + i; }
    else {
        int j = i - NX4;
        if (j >= NW4) return;
        v = w[j]; o = wbf + j;
    }
    ushort4 r;
    r.x = f2bf(v.x); r.y = f2bf(v.y); r.z = f2bf(v.z); r.w = f2bf(v.w);
    *o = r;
}

// ---------- 2/6. bf16 GEMM: BK=64, XOR-swizzled LDS, double-buffered ----------
// C[M,N] = A[M,K] * B[N,K]^T. 256 thr = 128x128 tile. LDS 64KB (2 bufs x 16KB x2).
// 16B slot s holds global (row = s>>3, kgroup = (s&7)^(row&7)); logical read of
// (row,kg) at slot row*8 + (kg^(row&7)) -> all-bank coverage for b128 frags.
__global__ __launch_bounds__(256) void gemm_bf16(const ushort* __restrict__ A,
                                                 const ushort* __restrict__ B,
                                                 float* __restrict__ C,
                                                 int M, int N, int K) {
    __shared__ __align__(16) ushort LA[2][8192];
    __shared__ __align__(16) ushort LB[2][8192];
    int tid = threadIdx.x;
    int w = tid >> 6, lane = tid & 63;
    int qm = lane & 15, quad = lane >> 4;
    int m0 = blockIdx.x * 128, n0 = blockIdx.y * 128;
    int mw = (w & 1) * 64, nw = (w >> 1) * 64;
    int sw = qm & 7;

    f32x4 acc[4][4];
#pragma unroll
    for (int i = 0; i < 4; i++)
#pragma unroll
        for (int j = 0; j < 4; j++) acc[i][j] = (f32x4){0.f, 0.f, 0.f, 0.f};

    // 1024 slots per tile buffer -> 4 per thread
    int s[4], rr[4], gg[4];
#pragma unroll
    for (int u = 0; u < 4; u++) {
        s[u] = tid + u * 256;
        rr[u] = s[u] >> 3;
        gg[u] = (s[u] & 7) ^ (rr[u] & 7);
    }

    auto do_stage = [&](int k0, int buf) {
#pragma unroll
        for (int u = 0; u < 4; u++)
            gld16(A + (size_t)(m0 + rr[u]) * K + k0 + gg[u] * 8, &LA[buf][s[u] * 8]);
#pragma unroll
        for (int u = 0; u < 4; u++)
            gld16(B + (size_t)(n0 + rr[u]) * K + k0 + gg[u] * 8, &LB[buf][s[u] * 8]);
    };

    do_stage(0, 0);
    int buf = 0;
    for (int k0 = 0; k0 < K; k0 += 64, buf ^= 1) {
        __syncthreads();
        if (k0 + 64 < K) do_stage(k0 + 64, buf ^ 1);
        bf16x8 a[4][2], bb[4][2];
#pragma unroll
        for (int mi = 0; mi < 4; mi++)
#pragma unroll
            for (int h = 0; h < 2; h++)
                a[mi][h] = *(const bf16x8*)&LA[buf][((mw + mi * 16 + qm) * 8 + ((h * 4 + quad) ^ sw)) * 8];
#pragma unroll
        for (int ni = 0; ni < 4; ni++)
#pragma unroll
            for (int h = 0; h < 2; h++)
                bb[ni][h] = *(const bf16x8*)&LB[buf][((nw + ni * 16 + qm) * 8 + ((h * 4 + quad) ^ sw)) * 8];
#pragma unroll
        for (int h = 0; h < 2; h++)
#pragma unroll
            for (int mi = 0; mi < 4; mi++)
#pragma unroll
                for (int ni = 0; ni < 4; ni++)
                    acc[mi][ni] = __builtin_amdgcn_mfma_f32_16x16x32_bf16(a[mi][h], bb[ni][h], acc[mi][ni], 0, 0, 0);
    }
#pragma unroll
    for (int mi = 0; mi < 4; mi++)
#pragma unroll
        for (int ni = 0; ni < 4; ni++) {
            int row = m0 + mw + mi * 16 + quad * 4;
            int col = n0 + nw + ni * 16 + qm;
            float* cp = C + (size_t)row * N + col;
#pragma unroll
            for (int r = 0; r < 4; r++) cp[(size_t)r * N] = acc[mi][ni][r];
        }
}

// ---------- 3. fused RMSNorm + RoPE ----------
__global__ __launch_bounds__(256) void normrope_kernel(const float* __restrict__ qkv,
                                                       const float* __restrict__ qw,
                                                       const float* __restrict__ kw,
                                                       ushort* __restrict__ Q,
                                                       ushort* __restrict__ Kb) {
    int r = blockIdx.x;          // b*2048 + t
    int b = r >> 11;
    int t = r & 2047;
    int tid = threadIdx.x;
    int w = tid >> 6;
    int lane = tid & 63;

    float inv_freq = __expf(-((float)(lane & 62) * (1.0f / 64.0f)) * 9.210340371976184f);
    float sn, cs;
    sincosf((float)t * inv_freq, &sn, &cs);

#pragma unroll
    for (int hg = 0; hg < 5; hg++) {
        int col = hg * 256 + w * 64 + lane;
        float v = qkv[(size_t)r * 1536 + col];
        float ss = v * v;
#pragma unroll
        for (int m = 1; m < 64; m <<= 1) ss += __shfl_xor(ss, m);
        float rinv = rsqrtf(ss * (1.0f / 64.0f) + 1.1920929e-7f);
        float wt = (hg < 4) ? qw[lane] : kw[lane];
        float vn = v * rinv * wt;
        float pr = __shfl_xor(vn, 1);
        float out = (lane & 1) ? fmaf(pr, sn, vn * cs) : fmaf(vn, cs, -pr * sn);
        if (hg < 4) {
            int h = hg * 4 + w;
            Q[((size_t)(b * 16 + h) * 2048 + t) * 64 + lane] = f2bf(out * 0.125f);
        } else {
            Kb[((size_t)(b * 4 + w) * 2048 + t) * 64 + lane] = f2bf(out);
        }
    }
}

// ---------- 4. V transpose ----------
__global__ __launch_bounds__(256) void vtrans_kernel(const float* __restrict__ qkv,
                                                     ushort* __restrict__ VT) {
    __shared__ float tile[64][65];
    int bkv = blockIdx.x;
    int t0 = blockIdx.y * 64;
    int b = bkv >> 2;
    int kvh = bkv & 3;
    int tid = threadIdx.x;
    int c = tid & 63;
    int rr = tid >> 6;
#pragma unroll
    for (int p = 0; p < 16; p++) {
        int tl = p * 4 + rr;
        tile[tl][c] = qkv[((size_t)(b * 2048) + t0 + tl) * 1536 + 1280 + kvh * 64 + c];
    }
    __syncthreads();
#pragma unroll
    for (int p = 0; p < 16; p++) {
        int dd = p * 4 + rr;
        VT[((size_t)bkv * 64 + dd) * 2048 + t0 + c] = f2bf(tile[c][dd]);
    }
}

// ---------- 5. attn v5: fixed-max softmax (scores provably <= 8), staged K/V ----------
// Block = pair of 64-row q-blocks {p, 31-p}: 33 uniform 64-key chunks; wave w
// owns 16 q-rows. RMS-normed rows => ||Q||=||K||=8 => score=Q.K/8 in [-8,8].
// p = exp2(score*log2e - 8*log2e): no running max, no rescale, no cross-lane
// in the chunk critical path (l reduced across quads once, in the epilogue).
__global__ __launch_bounds__(256) void attn5_kernel(const ushort* __restrict__ Q,
                                                    const ushort* __restrict__ K,
                                                    const ushort* __restrict__ VT,
                                                    ushort* __restrict__ O) {
    __shared__ __align__(16) ushort KT[2][4096];    // K chunk: 64 keys x 64 d
    __shared__ __align__(16) ushort VL[2][4096];    // V^T chunk: 64 d x 64 keys
    __shared__ __align__(16) ushort PBuf[4][1024];  // per-wave P: 16 q x 64 keys

    const float LOG2E = 1.4426950408889634f;
    const float C8 = 11.541560327111707f;           // 8 * log2(e)

    int blk = blockIdx.x;
    int bh = blk >> 4;                 // 0..31
    int p  = blk & 15;                 // pair index
    int tid = threadIdx.x;
    int w = tid >> 6, lane = tid & 63;
    int qm = lane & 15, quad = lane >> 4;
    int b = bh >> 4, h = bh & 15;
    int bkv = b * 4 + (h >> 2);

    const ushort* Qbh = Q + (size_t)bh * 2048 * 64;
    const ushort* Kbh = K + (size_t)bkv * 2048 * 64;
    const ushort* Vbh = VT + (size_t)bkv * 64 * 2048;
    ushort* pb = PBuf[w];
    int sw = qm & 7;

    int s0 = tid, s1 = tid + 256;
    int r0 = s0 >> 3, g0 = (s0 & 7) ^ (r0 & 7);
    int r1 = s1 >> 3, g1 = (s1 & 7) ^ (r1 & 7);

    auto do_stage = [&](int j0, int buf) {
        gld16(Kbh + (size_t)(j0 + r0) * 64 + g0 * 8, &KT[buf][s0 * 8]);
        gld16(Kbh + (size_t)(j0 + r1) * 64 + g1 * 8, &KT[buf][s1 * 8]);
        gld16(Vbh + (size_t)r0 * 2048 + j0 + g0 * 8, &VL[buf][s0 * 8]);
        gld16(Vbh + (size_t)r1 * 2048 + j0 + g1 * 8, &VL[buf][s1 * 8]);
    };

    int qblkA = p, qblkB = 31 - p;
    int nchA = qblkA + 1;
    const int total = 33;

    int q0 = qblkA * 64 + w * 16;
    const ushort* qptr = Qbh + (size_t)(q0 + qm) * 64 + quad * 8;
    bf16x8 qb0 = *(const bf16x8*)qptr;
    bf16x8 qb1 = *(const bf16x8*)(qptr + 32);
    f32x4 oacc[4];
    float lacc = 0.f;
#pragma unroll
    for (int i = 0; i < 4; i++) oacc[i] = (f32x4){0.f, 0.f, 0.f, 0.f};

    auto writeO = [&]() {
        float l = lacc;
        l += __shfl_xor(l, 16);
        l += __shfl_xor(l, 32);
        float rinv = 1.0f / l;
        uint2 val;
#pragma unroll
        for (int dt = 0; dt < 4; dt++) {
            val.x = pk2(oacc[dt][0] * rinv, oacc[dt][1] * rinv);
            val.y = pk2(oacc[dt][2] * rinv, oacc[dt][3] * rinv);
            *(uint2*)&O[((size_t)(b * 2048) + q0 + qm) * 1024 + h * 64 + dt * 16 + quad * 4] = val;
        }
    };

    do_stage(0, 0);
    int buf = 0;
#pragma unroll 1
    for (int i = 0; i < total; i++, buf ^= 1) {
        bool inB = (i >= nchA);
        int c = inB ? i - nchA : i;
        int j0 = c * 64;
        int nch = inB ? (qblkB + 1) : nchA;

        if (i == nchA) {               // tile switch: flush A, init B
            writeO();
            q0 = qblkB * 64 + w * 16;
            const ushort* qp2 = Qbh + (size_t)(q0 + qm) * 64 + quad * 8;
            qb0 = *(const bf16x8*)qp2;
            qb1 = *(const bf16x8*)(qp2 + 32);
            lacc = 0.f;
#pragma unroll
            for (int ii = 0; ii < 4; ii++) oacc[ii] = (f32x4){0.f, 0.f, 0.f, 0.f};
        }

        __syncthreads();               // staged buf ready
        int ni = i + 1;
        if (ni < total) do_stage(ni < nchA ? 64 * ni : 64 * (ni - nchA), buf ^ 1);

        // ---- S^T = K Q^T from LDS ----
        f32x4 st[4];
#pragma unroll
        for (int tj = 0; tj < 4; tj++) st[tj] = (f32x4){0.f, 0.f, 0.f, 0.f};
#pragma unroll
        for (int tj = 0; tj < 4; tj++) {
            bf16x8 kf0 = *(const bf16x8*)&KT[buf][((16 * tj + qm) * 8 + (quad ^ sw)) * 8];
            bf16x8 kf1 = *(const bf16x8*)&KT[buf][((16 * tj + qm) * 8 + ((4 + quad) ^ sw)) * 8];
            st[tj] = __builtin_amdgcn_mfma_f32_16x16x32_bf16(kf0, qb0, st[tj], 0, 0, 0);
            st[tj] = __builtin_amdgcn_mfma_f32_16x16x32_bf16(kf1, qb1, st[tj], 0, 0, 0);
        }
        // st[tj][r] = S^T[key = j0+16tj+4quad+r][q = q0+qm]
        if (c == nch - 1) {            // diagonal chunk: causal mask
#pragma unroll
            for (int tj = 0; tj < 4; tj++)
#pragma unroll
                for (int r = 0; r < 4; r++) {
                    int key = j0 + tj * 16 + quad * 4 + r;
                    if (key > q0 + qm) st[tj][r] = -1e30f;
                }
        }
        // ---- fixed-max softmax: p = exp2(s*log2e - 8*log2e) ----
        float rs = 0.f;
#pragma unroll
        for (int tj = 0; tj < 4; tj++)
#pragma unroll
            for (int r = 0; r < 4; r++) {
                float pv = fexp2(fmaf(st[tj][r], LOG2E, -C8));
                st[tj][r] = pv;
                rs += pv;
            }
        lacc += rs;                    // cross-quad reduction deferred to epilogue

        // ---- pack P^T (swizzled per-wave LDS, b64 writes) ----
#pragma unroll
        for (int tj = 0; tj < 4; tj++) {
            int g = 2 * tj + (quad >> 1);
            uint2 val;
            val.x = pk2(st[tj][0], st[tj][1]);
            val.y = pk2(st[tj][2], st[tj][3]);
            *(uint2*)&pb[(qm * 8 + (g ^ sw)) * 8 + (quad & 1) * 4] = val;
        }
        asm volatile("s_waitcnt lgkmcnt(0)" ::: "memory");

        // ---- O^T += V^T P^T (both from LDS) ----
#pragma unroll
        for (int half = 0; half < 2; half++) {
            int gg = 4 * half + quad;
            bf16x8 pfrag = *(const bf16x8*)&pb[(qm * 8 + (gg ^ sw)) * 8];
#pragma unroll
            for (int dt = 0; dt < 4; dt++) {
                bf16x8 vf = *(const bf16x8*)&VL[buf][((16 * dt + qm) * 8 + (gg ^ sw)) * 8];
                oacc[dt] = __builtin_amdgcn_mfma_f32_16x16x32_bf16(vf, pfrag, oacc[dt], 0, 0, 0);
            }
        }
    }
    writeO();                          // flush tile B
}

// ---------- launch ----------
extern "C" void kernel_launch(void* const* d_in, const int* in_sizes, int n_in,
                              void* d_out, int out_size, void* d_ws, size_t ws_size,
                              hipStream_t stream) {
    (void)in_sizes; (void)n_in; (void)out_size; (void)ws_size;
    const float* x    = (const float*)d_in[0];
    const float* qkvo = (const float*)d_in[1];
    const float* qw   = (const float*)d_in[2];
    const float* kw   = (const float*)d_in[3];
    float* out = (float*)d_out;

    char* ws = (char*)d_ws;
    ushort* xbf = (ushort*)(ws + 0);          //  8388608 B
    ushort* wbf = (ushort*)(ws + 8388608);    //  5242880 B
    float*  qkv = (float*)(ws + 13631488);    // 25165824 B
    ushort* Qb  = (ushort*)(ws + 38797312);   //  8388608 B
    ushort* Kb  = (ushort*)(ws + 47185920);   //  2097152 B
    ushort* VT  = (ushort*)(ws + 49283072);   //  2097152 B
    ushort* Ob  = (ushort*)(ws + 51380224);   //  8388608 B

    cast_kernel<<<6656, 256, 0, stream>>>((const float4*)x, (const float4*)qkvo,
                                          (ushort4*)xbf, (ushort4*)wbf);
    gemm_bf16<<<dim3(32, 12), 256, 0, stream>>>(xbf, wbf, qkv, 4096, 1536, 1024);
    normrope_kernel<<<4096, 256, 0, stream>>>(qkv, qw, kw, Qb, Kb);
    vtrans_kernel<<<dim3(8, 32), 256, 0, stream>>>(qkv, VT);
    attn5_kernel<<<512, 256, 0, stream>>>(Qb, Kb, VT, Ob);
    gemm_bf16<<<dim3(32, 8), 256, 0, stream>>>(Ob, wbf + (size_t)1536 * 1024, out, 4096, 1024, 1024);
}

// Round 7
// 159.731 us; speedup vs baseline: 2.8839x; 1.0756x over previous
//
#include <hip/hip_runtime.h>
#include <hip/hip_bf16.h>
#include <cstdint>
#include <cstddef>

// ---------- types ----------
typedef __bf16 bf16x8 __attribute__((ext_vector_type(8)));
typedef float f32x4 __attribute__((ext_vector_type(4)));

__device__ __forceinline__ unsigned short f2bf(float f) {
    unsigned u = __builtin_bit_cast(unsigned, f);
    u += 0x7FFFu + ((u >> 16) & 1u);   // round-to-nearest-even
    return (unsigned short)(u >> 16);
}
// packed f32x2 -> bf16x2 via native HW convert (RTNE)
__device__ __forceinline__ unsigned pk2(float a, float b) {
    typedef __bf16 bf16x2 __attribute__((ext_vector_type(2)));
    bf16x2 h;
    h[0] = (__bf16)a;
    h[1] = (__bf16)b;
    unsigned r;
    __builtin_memcpy(&r, &h, 4);
    return r;
}
__device__ __forceinline__ float fexp2(float x) {
#if __has_builtin(__builtin_amdgcn_exp2f)
    return __builtin_amdgcn_exp2f(x);
#else
    return __expf(x * 0.6931471805599453f);
#endif
}
// async global->LDS, 16B per lane. LDS dest must be uniform-base + lane*16.
__device__ __forceinline__ void gld16(const void* g, void* l) {
    __builtin_amdgcn_global_load_lds((const __attribute__((address_space(1))) void*)g,
                                     (__attribute__((address_space(3))) void*)l, 16, 0, 0);
}

// ---------- 1. fp32 -> bf16 cast ----------
__global__ __launch_bounds__(256) void cast_kernel(const float4* __restrict__ x,
                                                   const float4* __restrict__ w,
                                                   ushort4* __restrict__ xbf,
                                                   ushort4* __restrict__ wbf) {
    int i = blockIdx.x * 256 + threadIdx.x;
    const int NX4 = 4096 * 1024 / 4;
    const int NW4 = 2560 * 1024 / 4;
    float4 v;
    ushort4* o;
    if (i < NX4) { v = x[i]; o = xbf + i; }
    else {
        int j = i - NX4;
        if (j >= NW4) return;
        v = w[j]; o = wbf + j;
    }
    ushort4 r;
    r.x = f2bf(v.x); r.y = f2bf(v.y); r.z = f2bf(v.z); r.w = f2bf(v.w);
    *o = r;
}

// ---------- 2/6. bf16 GEMM: 64x128 tile, BK=64, XOR-swizzled LDS, dbuf ----------
// C[M,N] = A[M,K] * B[N,K]^T. 256 thr = 4 waves, each 32x64 (2x4 frags).
// Grid (M/64, N/128) -> 768 / 512 blocks: 2-3 blocks/CU oversubscription.
__global__ __launch_bounds__(256) void gemm_bf16(const ushort* __restrict__ A,
                                                 const ushort* __restrict__ B,
                                                 float* __restrict__ C,
                                                 int M, int N, int K) {
    __shared__ __align__(16) ushort LA[2][4096];   //  64 rows x 64 k
    __shared__ __align__(16) ushort LB[2][8192];   // 128 rows x 64 k
    int tid = threadIdx.x;
    int w = tid >> 6, lane = tid & 63;
    int qm = lane & 15, quad = lane >> 4;
    int m0 = blockIdx.x * 64, n0 = blockIdx.y * 128;
    int mw = (w & 1) * 32, nw = (w >> 1) * 64;
    int sw = qm & 7;

    f32x4 acc[2][4];
#pragma unroll
    for (int i = 0; i < 2; i++)
#pragma unroll
        for (int j = 0; j < 4; j++) acc[i][j] = (f32x4){0.f, 0.f, 0.f, 0.f};

    // A: 512 slots (2/thread); B: 1024 slots (4/thread). slot s -> row s>>3,
    // kgroup (s&7)^(row&7).
    int sa[2], ra[2], ga[2];
#pragma unroll
    for (int u = 0; u < 2; u++) {
        sa[u] = tid + u * 256;
        ra[u] = sa[u] >> 3;
        ga[u] = (sa[u] & 7) ^ (ra[u] & 7);
    }
    int sb[4], rb[4], gb[4];
#pragma unroll
    for (int u = 0; u < 4; u++) {
        sb[u] = tid + u * 256;
        rb[u] = sb[u] >> 3;
        gb[u] = (sb[u] & 7) ^ (rb[u] & 7);
    }

    auto do_stage = [&](int k0, int buf) {
#pragma unroll
        for (int u = 0; u < 2; u++)
            gld16(A + (size_t)(m0 + ra[u]) * K + k0 + ga[u] * 8, &LA[buf][sa[u] * 8]);
#pragma unroll
        for (int u = 0; u < 4; u++)
            gld16(B + (size_t)(n0 + rb[u]) * K + k0 + gb[u] * 8, &LB[buf][sb[u] * 8]);
    };

    do_stage(0, 0);
    int buf = 0;
    for (int k0 = 0; k0 < K; k0 += 64, buf ^= 1) {
        __syncthreads();
        if (k0 + 64 < K) do_stage(k0 + 64, buf ^ 1);
        bf16x8 a[2][2], bb[4][2];
#pragma unroll
        for (int mi = 0; mi < 2; mi++)
#pragma unroll
            for (int h = 0; h < 2; h++)
                a[mi][h] = *(const bf16x8*)&LA[buf][((mw + mi * 16 + qm) * 8 + ((h * 4 + quad) ^ sw)) * 8];
#pragma unroll
        for (int ni = 0; ni < 4; ni++)
#pragma unroll
            for (int h = 0; h < 2; h++)
                bb[ni][h] = *(const bf16x8*)&LB[buf][((nw + ni * 16 + qm) * 8 + ((h * 4 + quad) ^ sw)) * 8];
#pragma unroll
        for (int h = 0; h < 2; h++)
#pragma unroll
            for (int mi = 0; mi < 2; mi++)
#pragma unroll
                for (int ni = 0; ni < 4; ni++)
                    acc[mi][ni] = __builtin_amdgcn_mfma_f32_16x16x32_bf16(a[mi][h], bb[ni][h], acc[mi][ni], 0, 0, 0);
    }
#pragma unroll
    for (int mi = 0; mi < 2; mi++)
#pragma unroll
        for (int ni = 0; ni < 4; ni++) {
            int row = m0 + mw + mi * 16 + quad * 4;
            int col = n0 + nw + ni * 16 + qm;
            float* cp = C + (size_t)row * N + col;
#pragma unroll
            for (int r = 0; r < 4; r++) cp[(size_t)r * N] = acc[mi][ni][r];
        }
}

// ---------- 3. fused RMSNorm + RoPE ----------
__global__ __launch_bounds__(256) void normrope_kernel(const float* __restrict__ qkv,
                                                       const float* __restrict__ qw,
                                                       const float* __restrict__ kw,
                                                       ushort* __restrict__ Q,
                                                       ushort* __restrict__ Kb) {
    int r = blockIdx.x;          // b*2048 + t
    int b = r >> 11;
    int t = r & 2047;
    int tid = threadIdx.x;
    int w = tid >> 6;
    int lane = tid & 63;

    float inv_freq = __expf(-((float)(lane & 62) * (1.0f / 64.0f)) * 9.210340371976184f);
    float sn, cs;
    sincosf((float)t * inv_freq, &sn, &cs);

#pragma unroll
    for (int hg = 0; hg < 5; hg++) {
        int col = hg * 256 + w * 64 + lane;
        float v = qkv[(size_t)r * 1536 + col];
        float ss = v * v;
#pragma unroll
        for (int m = 1; m < 64; m <<= 1) ss += __shfl_xor(ss, m);
        float rinv = rsqrtf(ss * (1.0f / 64.0f) + 1.1920929e-7f);
        float wt = (hg < 4) ? qw[lane] : kw[lane];
        float vn = v * rinv * wt;
        float pr = __shfl_xor(vn, 1);
        float out = (lane & 1) ? fmaf(pr, sn, vn * cs) : fmaf(vn, cs, -pr * sn);
        if (hg < 4) {
            int h = hg * 4 + w;
            Q[((size_t)(b * 16 + h) * 2048 + t) * 64 + lane] = f2bf(out * 0.125f);
        } else {
            Kb[((size_t)(b * 4 + w) * 2048 + t) * 64 + lane] = f2bf(out);
        }
    }
}

// ---------- 4. V transpose ----------
__global__ __launch_bounds__(256) void vtrans_kernel(const float* __restrict__ qkv,
                                                     ushort* __restrict__ VT) {
    __shared__ float tile[64][65];
    int bkv = blockIdx.x;
    int t0 = blockIdx.y * 64;
    int b = bkv >> 2;
    int kvh = bkv & 3;
    int tid = threadIdx.x;
    int c = tid & 63;
    int rr = tid >> 6;
#pragma unroll
    for (int p = 0; p < 16; p++) {
        int tl = p * 4 + rr;
        tile[tl][c] = qkv[((size_t)(b * 2048) + t0 + tl) * 1536 + 1280 + kvh * 64 + c];
    }
    __syncthreads();
#pragma unroll
    for (int p = 0; p < 16; p++) {
        int dd = p * 4 + rr;
        VT[((size_t)bkv * 64 + dd) * 2048 + t0 + c] = f2bf(tile[c][dd]);
    }
}

// ---------- 5. attn v6: un-paired q-blocks, longest-first, fixed-max softmax ----------
// Block = one 64-row q-block; grid 1024 = 4 blocks/CU (40KB LDS), dispatched
// longest-first (qp = 31 - blk>>5) so list scheduling balances the causal skew.
// Wave w owns 16 q-rows. p = exp2(s*log2e - 8*log2e) (scores provably in [-8,8]).
__global__ __launch_bounds__(256) void attn6_kernel(const ushort* __restrict__ Q,
                                                    const ushort* __restrict__ K,
                                                    const ushort* __restrict__ VT,
                                                    ushort* __restrict__ O) {
    __shared__ __align__(16) ushort KT[2][4096];    // K chunk: 64 keys x 64 d
    __shared__ __align__(16) ushort VL[2][4096];    // V^T chunk: 64 d x 64 keys
    __shared__ __align__(16) ushort PBuf[4][1024];  // per-wave P: 16 q x 64 keys

    const float LOG2E = 1.4426950408889634f;
    const float C8 = 11.541560327111707f;           // 8 * log2(e)

    int blk = blockIdx.x;
    int qp = 31 - (blk >> 5);          // longest blocks dispatch first
    int bh = blk & 31;
    int tid = threadIdx.x;
    int w = tid >> 6, lane = tid & 63;
    int qm = lane & 15, quad = lane >> 4;
    int b = bh >> 4, h = bh & 15;
    int bkv = b * 4 + (h >> 2);

    const ushort* Qbh = Q + (size_t)bh * 2048 * 64;
    const ushort* Kbh = K + (size_t)bkv * 2048 * 64;
    const ushort* Vbh = VT + (size_t)bkv * 64 * 2048;
    ushort* pb = PBuf[w];
    int sw = qm & 7;

    int s0 = tid, s1 = tid + 256;
    int r0 = s0 >> 3, g0 = (s0 & 7) ^ (r0 & 7);
    int r1 = s1 >> 3, g1 = (s1 & 7) ^ (r1 & 7);

    auto do_stage = [&](int j0, int buf) {
        gld16(Kbh + (size_t)(j0 + r0) * 64 + g0 * 8, &KT[buf][s0 * 8]);
        gld16(Kbh + (size_t)(j0 + r1) * 64 + g1 * 8, &KT[buf][s1 * 8]);
        gld16(Vbh + (size_t)r0 * 2048 + j0 + g0 * 8, &VL[buf][s0 * 8]);
        gld16(Vbh + (size_t)r1 * 2048 + j0 + g1 * 8, &VL[buf][s1 * 8]);
    };

    int nch = qp + 1;
    int q0 = qp * 64 + w * 16;
    const ushort* qptr = Qbh + (size_t)(q0 + qm) * 64 + quad * 8;
    bf16x8 qb0 = *(const bf16x8*)qptr;
    bf16x8 qb1 = *(const bf16x8*)(qptr + 32);
    f32x4 oacc[4];
    float lacc = 0.f;
#pragma unroll
    for (int i = 0; i < 4; i++) oacc[i] = (f32x4){0.f, 0.f, 0.f, 0.f};

    do_stage(0, 0);
    int buf = 0;
#pragma unroll 1
    for (int i = 0; i < nch; i++, buf ^= 1) {
        int j0 = i * 64;
        __syncthreads();               // staged buf ready
        if (i + 1 < nch) do_stage(j0 + 64, buf ^ 1);

        // ---- S^T = K Q^T from LDS ----
        f32x4 st[4];
#pragma unroll
        for (int tj = 0; tj < 4; tj++) st[tj] = (f32x4){0.f, 0.f, 0.f, 0.f};
#pragma unroll
        for (int tj = 0; tj < 4; tj++) {
            bf16x8 kf0 = *(const bf16x8*)&KT[buf][((16 * tj + qm) * 8 + (quad ^ sw)) * 8];
            bf16x8 kf1 = *(const bf16x8*)&KT[buf][((16 * tj + qm) * 8 + ((4 + quad) ^ sw)) * 8];
            st[tj] = __builtin_amdgcn_mfma_f32_16x16x32_bf16(kf0, qb0, st[tj], 0, 0, 0);
            st[tj] = __builtin_amdgcn_mfma_f32_16x16x32_bf16(kf1, qb1, st[tj], 0, 0, 0);
        }
        // st[tj][r] = S^T[key = j0+16tj+4quad+r][q = q0+qm]
        if (i == nch - 1) {            // diagonal chunk: causal mask
#pragma unroll
            for (int tj = 0; tj < 4; tj++)
#pragma unroll
                for (int r = 0; r < 4; r++) {
                    int key = j0 + tj * 16 + quad * 4 + r;
                    if (key > q0 + qm) st[tj][r] = -1e30f;
                }
        }
        // ---- fixed-max softmax ----
        float rs = 0.f;
#pragma unroll
        for (int tj = 0; tj < 4; tj++)
#pragma unroll
            for (int r = 0; r < 4; r++) {
                float pv = fexp2(fmaf(st[tj][r], LOG2E, -C8));
                st[tj][r] = pv;
                rs += pv;
            }
        lacc += rs;                    // cross-quad reduce deferred to epilogue

        // ---- pack P^T (swizzled per-wave LDS, b64 writes) ----
#pragma unroll
        for (int tj = 0; tj < 4; tj++) {
            int g = 2 * tj + (quad >> 1);
            uint2 val;
            val.x = pk2(st[tj][0], st[tj][1]);
            val.y = pk2(st[tj][2], st[tj][3]);
            *(uint2*)&pb[(qm * 8 + (g ^ sw)) * 8 + (quad & 1) * 4] = val;
        }
        asm volatile("s_waitcnt lgkmcnt(0)" ::: "memory");

        // ---- O^T += V^T P^T (both from LDS) ----
#pragma unroll
        for (int half = 0; half < 2; half++) {
            int gg = 4 * half + quad;
            bf16x8 pfrag = *(const bf16x8*)&pb[(qm * 8 + (gg ^ sw)) * 8];
#pragma unroll
            for (int dt = 0; dt < 4; dt++) {
                bf16x8 vf = *(const bf16x8*)&VL[buf][((16 * dt + qm) * 8 + (gg ^ sw)) * 8];
                oacc[dt] = __builtin_amdgcn_mfma_f32_16x16x32_bf16(vf, pfrag, oacc[dt], 0, 0, 0);
            }
        }
    }
    // ---- epilogue ----
    float l = lacc;
    l += __shfl_xor(l, 16);
    l += __shfl_xor(l, 32);
    float rinv = 1.0f / l;
    uint2 val;
#pragma unroll
    for (int dt = 0; dt < 4; dt++) {
        val.x = pk2(oacc[dt][0] * rinv, oacc[dt][1] * rinv);
        val.y = pk2(oacc[dt][2] * rinv, oacc[dt][3] * rinv);
        *(uint2*)&O[((size_t)(b * 2048) + q0 + qm) * 1024 + h * 64 + dt * 16 + quad * 4] = val;
    }
}

// ---------- launch ----------
extern "C" void kernel_launch(void* const* d_in, const int* in_sizes, int n_in,
                              void* d_out, int out_size, void* d_ws, size_t ws_size,
                              hipStream_t stream) {
    (void)in_sizes; (void)n_in; (void)out_size; (void)ws_size;
    const float* x    = (const float*)d_in[0];
    const float* qkvo = (const float*)d_in[1];
    const float* qw   = (const float*)d_in[2];
    const float* kw   = (const float*)d_in[3];
    float* out = (float*)d_out;

    char* ws = (char*)d_ws;
    ushort* xbf = (ushort*)(ws + 0);          //  8388608 B
    ushort* wbf = (ushort*)(ws + 8388608);    //  5242880 B
    float*  qkv = (float*)(ws + 13631488);    // 25165824 B
    ushort* Qb  = (ushort*)(ws + 38797312);   //  8388608 B
    ushort* Kb  = (ushort*)(ws + 47185920);   //  2097152 B
    ushort* VT  = (ushort*)(ws + 49283072);   //  2097152 B
    ushort* Ob  = (ushort*)(ws + 51380224);   //  8388608 B

    cast_kernel<<<6656, 256, 0, stream>>>((const float4*)x, (const float4*)qkvo,
                                          (ushort4*)xbf, (ushort4*)wbf);
    gemm_bf16<<<dim3(64, 12), 256, 0, stream>>>(xbf, wbf, qkv, 4096, 1536, 1024);
    normrope_kernel<<<4096, 256, 0, stream>>>(qkv, qw, kw, Qb, Kb);
    vtrans_kernel<<<dim3(8, 32), 256, 0, stream>>>(qkv, VT);
    attn6_kernel<<<1024, 256, 0, stream>>>(Qb, Kb, VT, Ob);
    gemm_bf16<<<dim3(64, 8), 256, 0, stream>>>(Ob, wbf + (size_t)1536 * 1024, out, 4096, 1024, 1024);
}

// Round 8
// 158.224 us; speedup vs baseline: 2.9113x; 1.0095x over previous
//
#include <hip/hip_runtime.h>
#include <hip/hip_bf16.h>
#include <cstdint>
#include <cstddef>

// ---------- types ----------
typedef __bf16 bf16x8 __attribute__((ext_vector_type(8)));
typedef float f32x4 __attribute__((ext_vector_type(4)));

__device__ __forceinline__ unsigned short f2bf(float f) {
    unsigned u = __builtin_bit_cast(unsigned, f);
    u += 0x7FFFu + ((u >> 16) & 1u);   // round-to-nearest-even
    return (unsigned short)(u >> 16);
}
// packed f32x2 -> bf16x2 via native HW convert (RTNE)
__device__ __forceinline__ unsigned pk2(float a, float b) {
    typedef __bf16 bf16x2 __attribute__((ext_vector_type(2)));
    bf16x2 h;
    h[0] = (__bf16)a;
    h[1] = (__bf16)b;
    unsigned r;
    __builtin_memcpy(&r, &h, 4);
    return r;
}
__device__ __forceinline__ float fexp2(float x) {
#if __has_builtin(__builtin_amdgcn_exp2f)
    return __builtin_amdgcn_exp2f(x);
#else
    return __expf(x * 0.6931471805599453f);
#endif
}
// async global->LDS, 16B per lane. LDS dest must be uniform-base + lane*16.
__device__ __forceinline__ void gld16(const void* g, void* l) {
    __builtin_amdgcn_global_load_lds((const __attribute__((address_space(1))) void*)g,
                                     (__attribute__((address_space(3))) void*)l, 16, 0, 0);
}

// ---------- 1. fp32 -> bf16 cast ----------
__global__ __launch_bounds__(256) void cast_kernel(const float4* __restrict__ x,
                                                   const float4* __restrict__ w,
                                                   ushort4* __restrict__ xbf,
                                                   ushort4* __restrict__ wbf) {
    int i = blockIdx.x * 256 + threadIdx.x;
    const int NX4 = 4096 * 1024 / 4;
    const int NW4 = 2560 * 1024 / 4;
    float4 v;
    ushort4* o;
    if (i < NX4) { v = x[i]; o = xbf + i; }
    else {
        int j = i - NX4;
        if (j >= NW4) return;
        v = w[j]; o = wbf + j;
    }
    ushort4 r;
    r.x = f2bf(v.x); r.y = f2bf(v.y); r.z = f2bf(v.z); r.w = f2bf(v.w);
    *o = r;
}

// ---------- 2/6. bf16 GEMM: 64x128 tile, BK=64, XOR-swizzled LDS, dbuf ----------
__global__ __launch_bounds__(256) void gemm_bf16(const ushort* __restrict__ A,
                                                 const ushort* __restrict__ B,
                                                 float* __restrict__ C,
                                                 int M, int N, int K) {
    __shared__ __align__(16) ushort LA[2][4096];   //  64 rows x 64 k
    __shared__ __align__(16) ushort LB[2][8192];   // 128 rows x 64 k
    int tid = threadIdx.x;
    int w = tid >> 6, lane = tid & 63;
    int qm = lane & 15, quad = lane >> 4;
    int m0 = blockIdx.x * 64, n0 = blockIdx.y * 128;
    int mw = (w & 1) * 32, nw = (w >> 1) * 64;
    int sw = qm & 7;

    f32x4 acc[2][4];
#pragma unroll
    for (int i = 0; i < 2; i++)
#pragma unroll
        for (int j = 0; j < 4; j++) acc[i][j] = (f32x4){0.f, 0.f, 0.f, 0.f};

    int sa[2], ra[2], ga[2];
#pragma unroll
    for (int u = 0; u < 2; u++) {
        sa[u] = tid + u * 256;
        ra[u] = sa[u] >> 3;
        ga[u] = (sa[u] & 7) ^ (ra[u] & 7);
    }
    int sb[4], rb[4], gb[4];
#pragma unroll
    for (int u = 0; u < 4; u++) {
        sb[u] = tid + u * 256;
        rb[u] = sb[u] >> 3;
        gb[u] = (sb[u] & 7) ^ (rb[u] & 7);
    }

    auto do_stage = [&](int k0, int buf) {
#pragma unroll
        for (int u = 0; u < 2; u++)
            gld16(A + (size_t)(m0 + ra[u]) * K + k0 + ga[u] * 8, &LA[buf][sa[u] * 8]);
#pragma unroll
        for (int u = 0; u < 4; u++)
            gld16(B + (size_t)(n0 + rb[u]) * K + k0 + gb[u] * 8, &LB[buf][sb[u] * 8]);
    };

    do_stage(0, 0);
    int buf = 0;
    for (int k0 = 0; k0 < K; k0 += 64, buf ^= 1) {
        __syncthreads();
        if (k0 + 64 < K) do_stage(k0 + 64, buf ^ 1);
        bf16x8 a[2][2], bb[4][2];
#pragma unroll
        for (int mi = 0; mi < 2; mi++)
#pragma unroll
            for (int h = 0; h < 2; h++)
                a[mi][h] = *(const bf16x8*)&LA[buf][((mw + mi * 16 + qm) * 8 + ((h * 4 + quad) ^ sw)) * 8];
#pragma unroll
        for (int ni = 0; ni < 4; ni++)
#pragma unroll
            for (int h = 0; h < 2; h++)
                bb[ni][h] = *(const bf16x8*)&LB[buf][((nw + ni * 16 + qm) * 8 + ((h * 4 + quad) ^ sw)) * 8];
#pragma unroll
        for (int h = 0; h < 2; h++)
#pragma unroll
            for (int mi = 0; mi < 2; mi++)
#pragma unroll
                for (int ni = 0; ni < 4; ni++)
                    acc[mi][ni] = __builtin_amdgcn_mfma_f32_16x16x32_bf16(a[mi][h], bb[ni][h], acc[mi][ni], 0, 0, 0);
    }
#pragma unroll
    for (int mi = 0; mi < 2; mi++)
#pragma unroll
        for (int ni = 0; ni < 4; ni++) {
            int row = m0 + mw + mi * 16 + quad * 4;
            int col = n0 + nw + ni * 16 + qm;
            float* cp = C + (size_t)row * N + col;
#pragma unroll
            for (int r = 0; r < 4; r++) cp[(size_t)r * N] = acc[mi][ni][r];
        }
}

// ---------- 3. fused RMSNorm + RoPE ----------
__global__ __launch_bounds__(256) void normrope_kernel(const float* __restrict__ qkv,
                                                       const float* __restrict__ qw,
                                                       const float* __restrict__ kw,
                                                       ushort* __restrict__ Q,
                                                       ushort* __restrict__ Kb) {
    int r = blockIdx.x;          // b*2048 + t
    int b = r >> 11;
    int t = r & 2047;
    int tid = threadIdx.x;
    int w = tid >> 6;
    int lane = tid & 63;

    float inv_freq = __expf(-((float)(lane & 62) * (1.0f / 64.0f)) * 9.210340371976184f);
    float sn, cs;
    sincosf((float)t * inv_freq, &sn, &cs);

#pragma unroll
    for (int hg = 0; hg < 5; hg++) {
        int col = hg * 256 + w * 64 + lane;
        float v = qkv[(size_t)r * 1536 + col];
        float ss = v * v;
#pragma unroll
        for (int m = 1; m < 64; m <<= 1) ss += __shfl_xor(ss, m);
        float rinv = rsqrtf(ss * (1.0f / 64.0f) + 1.1920929e-7f);
        float wt = (hg < 4) ? qw[lane] : kw[lane];
        float vn = v * rinv * wt;
        float pr = __shfl_xor(vn, 1);
        float out = (lane & 1) ? fmaf(pr, sn, vn * cs) : fmaf(vn, cs, -pr * sn);
        if (hg < 4) {
            int h = hg * 4 + w;
            Q[((size_t)(b * 16 + h) * 2048 + t) * 64 + lane] = f2bf(out * 0.125f);
        } else {
            Kb[((size_t)(b * 4 + w) * 2048 + t) * 64 + lane] = f2bf(out);
        }
    }
}

// ---------- 4. V transpose with PERMUTED key order ----------
// VT_perm[d][ (kk & ~31) + q2*8 + t*4 + r ] = V^T[d][kk], where within each
// 32-key block kk&31 = 16t + 4*q2 + r. This matches the MFMA k-permutation
// pi(quad*8+j) = 16*(j>>2) + 4*quad + (j&3) used by attn's PV step, so P in
// C-layout feeds the B-operand directly and V-frags are contiguous b128.
__global__ __launch_bounds__(256) void vtrans_kernel(const float* __restrict__ qkv,
                                                     ushort* __restrict__ VT) {
    __shared__ float tile[64][65];
    int bkv = blockIdx.x;
    int t0 = blockIdx.y * 64;
    int b = bkv >> 2;
    int kvh = bkv & 3;
    int tid = threadIdx.x;
    int c = tid & 63;
    int rr = tid >> 6;
#pragma unroll
    for (int p = 0; p < 16; p++) {
        int tl = p * 4 + rr;
        tile[tl][c] = qkv[((size_t)(b * 2048) + t0 + tl) * 1536 + 1280 + kvh * 64 + c];
    }
    __syncthreads();
    // permuted column within each 32-block
    int w5 = c & 31;
    int pc = (c & 32) + ((w5 >> 2) & 3) * 8 + (w5 >> 4) * 4 + (w5 & 3);
#pragma unroll
    for (int p = 0; p < 16; p++) {
        int dd = p * 4 + rr;
        VT[((size_t)bkv * 64 + dd) * 2048 + t0 + pc] = f2bf(tile[c][dd]);
    }
}

// ---------- 5. attn v7: register-resident P (k-permutation), no P LDS ----------
// Block = one 64-row q-block, longest-first. Wave w owns 16 q-rows.
// S^T = K*Q^T in C-layout; P = exp2(s*log2e - 8*log2e) packed straight into
// the PV B-operand registers; V^T staged in LDS already key-permuted.
__global__ __launch_bounds__(256) void attn7_kernel(const ushort* __restrict__ Q,
                                                    const ushort* __restrict__ K,
                                                    const ushort* __restrict__ VT,
                                                    ushort* __restrict__ O) {
    __shared__ __align__(16) ushort KT[2][4096];    // K chunk: 64 keys x 64 d
    __shared__ __align__(16) ushort VL[2][4096];    // V^T chunk (key-permuted)

    const float LOG2E = 1.4426950408889634f;
    const float C8 = 11.541560327111707f;           // 8 * log2(e)

    int blk = blockIdx.x;
    int qp = 31 - (blk >> 5);          // longest blocks dispatch first
    int bh = blk & 31;
    int tid = threadIdx.x;
    int w = tid >> 6, lane = tid & 63;
    int qm = lane & 15, quad = lane >> 4;
    int b = bh >> 4, h = bh & 15;
    int bkv = b * 4 + (h >> 2);

    const ushort* Qbh = Q + (size_t)bh * 2048 * 64;
    const ushort* Kbh = K + (size_t)bkv * 2048 * 64;
    const ushort* Vbh = VT + (size_t)bkv * 64 * 2048;
    int sw = qm & 7;

    int s0 = tid, s1 = tid + 256;
    int r0 = s0 >> 3, g0 = (s0 & 7) ^ (r0 & 7);
    int r1 = s1 >> 3, g1 = (s1 & 7) ^ (r1 & 7);

    auto do_stage = [&](int j0, int buf) {
        gld16(Kbh + (size_t)(j0 + r0) * 64 + g0 * 8, &KT[buf][s0 * 8]);
        gld16(Kbh + (size_t)(j0 + r1) * 64 + g1 * 8, &KT[buf][s1 * 8]);
        gld16(Vbh + (size_t)r0 * 2048 + j0 + g0 * 8, &VL[buf][s0 * 8]);
        gld16(Vbh + (size_t)r1 * 2048 + j0 + g1 * 8, &VL[buf][s1 * 8]);
    };

    int nch = qp + 1;
    int q0 = qp * 64 + w * 16;
    const ushort* qptr = Qbh + (size_t)(q0 + qm) * 64 + quad * 8;
    bf16x8 qb0 = *(const bf16x8*)qptr;
    bf16x8 qb1 = *(const bf16x8*)(qptr + 32);
    f32x4 oacc[4];
    float lacc = 0.f;
#pragma unroll
    for (int i = 0; i < 4; i++) oacc[i] = (f32x4){0.f, 0.f, 0.f, 0.f};

    do_stage(0, 0);
    int buf = 0;
#pragma unroll 1
    for (int i = 0; i < nch; i++, buf ^= 1) {
        int j0 = i * 64;
        __syncthreads();               // staged buf ready
        if (i + 1 < nch) do_stage(j0 + 64, buf ^ 1);

        // ---- S^T = K Q^T from LDS ----
        f32x4 st[4];
#pragma unroll
        for (int tj = 0; tj < 4; tj++) st[tj] = (f32x4){0.f, 0.f, 0.f, 0.f};
#pragma unroll
        for (int tj = 0; tj < 4; tj++) {
            bf16x8 kf0 = *(const bf16x8*)&KT[buf][((16 * tj + qm) * 8 + (quad ^ sw)) * 8];
            bf16x8 kf1 = *(const bf16x8*)&KT[buf][((16 * tj + qm) * 8 + ((4 + quad) ^ sw)) * 8];
            st[tj] = __builtin_amdgcn_mfma_f32_16x16x32_bf16(kf0, qb0, st[tj], 0, 0, 0);
            st[tj] = __builtin_amdgcn_mfma_f32_16x16x32_bf16(kf1, qb1, st[tj], 0, 0, 0);
        }
        // st[tj][r] = S^T[key = j0+16tj+4quad+r][q = q0+qm]
        if (i == nch - 1) {            // diagonal chunk: causal mask
#pragma unroll
            for (int tj = 0; tj < 4; tj++)
#pragma unroll
                for (int r = 0; r < 4; r++) {
                    int key = j0 + tj * 16 + quad * 4 + r;
                    if (key > q0 + qm) st[tj][r] = -1e30f;
                }
        }
        // ---- fixed-max softmax (scores provably in [-8,8]) ----
        float rs = 0.f;
#pragma unroll
        for (int tj = 0; tj < 4; tj++)
#pragma unroll
            for (int r = 0; r < 4; r++) {
                float pv = fexp2(fmaf(st[tj][r], LOG2E, -C8));
                st[tj][r] = pv;
                rs += pv;
            }
        lacc += rs;

        // ---- pack P straight into PV B-operand regs (k-permuted) ----
        unsigned up[4];
        up[0] = pk2(st[0][0], st[0][1]);
        up[1] = pk2(st[0][2], st[0][3]);
        up[2] = pk2(st[1][0], st[1][1]);
        up[3] = pk2(st[1][2], st[1][3]);
        bf16x8 pf0;
        __builtin_memcpy(&pf0, up, 16);
        up[0] = pk2(st[2][0], st[2][1]);
        up[1] = pk2(st[2][2], st[2][3]);
        up[2] = pk2(st[3][0], st[3][1]);
        up[3] = pk2(st[3][2], st[3][3]);
        bf16x8 pf1;
        __builtin_memcpy(&pf1, up, 16);

        // ---- O^T += V^T P^T (V frags from permuted LDS; P from registers) ----
#pragma unroll
        for (int dt = 0; dt < 4; dt++) {
            bf16x8 vf0 = *(const bf16x8*)&VL[buf][((16 * dt + qm) * 8 + (quad ^ sw)) * 8];
            bf16x8 vf1 = *(const bf16x8*)&VL[buf][((16 * dt + qm) * 8 + ((4 + quad) ^ sw)) * 8];
            oacc[dt] = __builtin_amdgcn_mfma_f32_16x16x32_bf16(vf0, pf0, oacc[dt], 0, 0, 0);
            oacc[dt] = __builtin_amdgcn_mfma_f32_16x16x32_bf16(vf1, pf1, oacc[dt], 0, 0, 0);
        }
    }
    // ---- epilogue ----
    float l = lacc;
    l += __shfl_xor(l, 16);
    l += __shfl_xor(l, 32);
    float rinv = 1.0f / l;
    uint2 val;
#pragma unroll
    for (int dt = 0; dt < 4; dt++) {
        val.x = pk2(oacc[dt][0] * rinv, oacc[dt][1] * rinv);
        val.y = pk2(oacc[dt][2] * rinv, oacc[dt][3] * rinv);
        *(uint2*)&O[((size_t)(b * 2048) + q0 + qm) * 1024 + h * 64 + dt * 16 + quad * 4] = val;
    }
}

// ---------- launch ----------
extern "C" void kernel_launch(void* const* d_in, const int* in_sizes, int n_in,
                              void* d_out, int out_size, void* d_ws, size_t ws_size,
                              hipStream_t stream) {
    (void)in_sizes; (void)n_in; (void)out_size; (void)ws_size;
    const float* x    = (const float*)d_in[0];
    const float* qkvo = (const float*)d_in[1];
    const float* qw   = (const float*)d_in[2];
    const float* kw   = (const float*)d_in[3];
    float* out = (float*)d_out;

    char* ws = (char*)d_ws;
    ushort* xbf = (ushort*)(ws + 0);          //  8388608 B
    ushort* wbf = (ushort*)(ws + 8388608);    //  5242880 B
    float*  qkv = (float*)(ws + 13631488);    // 25165824 B
    ushort* Qb  = (ushort*)(ws + 38797312);   //  8388608 B
    ushort* Kb  = (ushort*)(ws + 47185920);   //  2097152 B
    ushort* VT  = (ushort*)(ws + 49283072);   //  2097152 B
    ushort* Ob  = (ushort*)(ws + 51380224);   //  8388608 B

    cast_kernel<<<6656, 256, 0, stream>>>((const float4*)x, (const float4*)qkvo,
                                          (ushort4*)xbf, (ushort4*)wbf);
    gemm_bf16<<<dim3(64, 12), 256, 0, stream>>>(xbf, wbf, qkv, 4096, 1536, 1024);
    normrope_kernel<<<4096, 256, 0, stream>>>(qkv, qw, kw, Qb, Kb);
    vtrans_kernel<<<dim3(8, 32), 256, 0, stream>>>(qkv, VT);
    attn7_kernel<<<1024, 256, 0, stream>>>(Qb, Kb, VT, Ob);
    gemm_bf16<<<dim3(64, 8), 256, 0, stream>>>(Ob, wbf + (size_t)1536 * 1024, out, 4096, 1024, 1024);
}